// Round 1
// baseline (12550.187 us; speedup 1.0000x reference)
//
#include <hip/hip_runtime.h>
#include <math.h>

#define DD 256
#define NH 8
#define HDIM 32
#define NLAY 6
#define NQRY 100
#define TT 101
#define BB 8
#define NN 4096
#define NTXT 32
#define FFD 2048
#define MM (BB*TT)      // 808
#define BNN (BB*NN)     // 32768
#define KCH 8
#define KPC (NN/KCH)    // 512
#define KTILE 128
#define NQI 13          // queries per 32-lane group (g + 8*qi <= 100)

// ---------------------------------------------------------------- mem = img + enc @ wpeW + wpeb
__global__ __launch_bounds__(256) void k_mem(const float* __restrict__ img,
                                             const float* __restrict__ pm,
                                             const float* __restrict__ wpeW,
                                             const float* __restrict__ wpeb,
                                             float* __restrict__ mem) {
  int r0 = blockIdx.x * 4;
  __shared__ float enc[4][60];
  int t = threadIdx.x;
  if (t < 240) {
    int r = t / 60, i = t % 60;
    int c = i / 20, jj = i % 20;
    float p = pm[(size_t)(r0 + r) * 3 + c];
    float f = (float)(1 << (jj % 10));   // FREQS = 2^0..2^9 (geomspace(1,512,10) in f32)
    float a = p * f;
    enc[r][i] = (jj < 10) ? sinf(a) : cosf(a);
  }
  __syncthreads();
  int d = t;
  float bv = wpeb[d];
  float a0 = bv + img[(size_t)(r0 + 0) * DD + d];
  float a1 = bv + img[(size_t)(r0 + 1) * DD + d];
  float a2 = bv + img[(size_t)(r0 + 2) * DD + d];
  float a3 = bv + img[(size_t)(r0 + 3) * DD + d];
  for (int i = 0; i < 60; ++i) {
    float w = wpeW[i * DD + d];
    a0 += enc[0][i] * w;
    a1 += enc[1][i] * w;
    a2 += enc[2][i] * w;
    a3 += enc[3][i] * w;
  }
  mem[(size_t)(r0 + 0) * DD + d] = a0;
  mem[(size_t)(r0 + 1) * DD + d] = a1;
  mem[(size_t)(r0 + 2) * DD + d] = a2;
  mem[(size_t)(r0 + 3) * DD + d] = a3;
}

// ------------------------------------------------- y = act(x @ W + b), K=N=256, 8 rows/block
__global__ __launch_bounds__(256) void k_linear256(const float* __restrict__ x,
                                                   const float* __restrict__ W,
                                                   const float* __restrict__ b,
                                                   float* __restrict__ y,
                                                   int Mr, int relu) {
  int r0 = blockIdx.x * 8;
  int d = threadIdx.x;
  __shared__ float xs[8][DD];
  for (int i = threadIdx.x; i < 8 * DD; i += 256) {
    int r = i >> 8, k = i & 255;
    xs[r][k] = (r0 + r < Mr) ? x[(size_t)(r0 + r) * DD + k] : 0.f;
  }
  __syncthreads();
  float acc[8] = {0.f, 0.f, 0.f, 0.f, 0.f, 0.f, 0.f, 0.f};
  for (int k = 0; k < DD; ++k) {
    float w = W[k * DD + d];
#pragma unroll
    for (int r = 0; r < 8; ++r) acc[r] += xs[r][k] * w;
  }
  float bb = b[d];
#pragma unroll
  for (int r = 0; r < 8; ++r) {
    if (r0 + r < Mr) {
      float v = acc[r] + bb;
      if (relu) v = fmaxf(v, 0.f);
      y[(size_t)(r0 + r) * DD + d] = v;
    }
  }
}

// ------------------------------------------- generic tiled GEMM: C = act(A[M,K] @ W[K,N] + b)
__global__ __launch_bounds__(256) void k_gemm(const float* __restrict__ A,
                                              const float* __restrict__ W,
                                              const float* __restrict__ bias,
                                              float* __restrict__ C,
                                              int Mr, int K, int Nc, int relu) {
  __shared__ float As[16][65];
  __shared__ float Bs[16][65];
  int r0 = blockIdx.x * 64, c0 = blockIdx.y * 64;
  int tx = threadIdx.x & 15, ty = threadIdx.x >> 4;
  float acc[4][4] = {};
  for (int k0 = 0; k0 < K; k0 += 16) {
    for (int i = threadIdx.x; i < 64 * 16; i += 256) {
      int r = i >> 4, kk = i & 15;
      As[kk][r] = (r0 + r < Mr) ? A[(size_t)(r0 + r) * K + k0 + kk] : 0.f;
    }
    for (int i = threadIdx.x; i < 16 * 64; i += 256) {
      int kk = i >> 6, c = i & 63;
      Bs[kk][c] = W[(size_t)(k0 + kk) * Nc + c0 + c];
    }
    __syncthreads();
#pragma unroll
    for (int kk = 0; kk < 16; ++kk) {
      float a[4], bv[4];
#pragma unroll
      for (int u = 0; u < 4; ++u) a[u] = As[kk][ty * 4 + u];
#pragma unroll
      for (int u = 0; u < 4; ++u) bv[u] = Bs[kk][tx * 4 + u];
#pragma unroll
      for (int u = 0; u < 4; ++u)
#pragma unroll
        for (int v = 0; v < 4; ++v) acc[u][v] += a[u] * bv[v];
    }
    __syncthreads();
  }
#pragma unroll
  for (int u = 0; u < 4; ++u) {
    int r = r0 + ty * 4 + u;
    if (r >= Mr) continue;
#pragma unroll
    for (int v = 0; v < 4; ++v) {
      int c = c0 + tx * 4 + v;
      float val = acc[u][v] + bias[c];
      if (relu) val = fmaxf(val, 0.f);
      C[(size_t)r * Nc + c] = val;
    }
  }
}

// ---------------------------------------------------------- out = LN(xin (+delta)) * g + b
__global__ __launch_bounds__(256) void k_add_ln(const float* __restrict__ xin,
                                                const float* __restrict__ delta,
                                                const float* __restrict__ g,
                                                const float* __restrict__ bb,
                                                float* __restrict__ out) {
  int row = blockIdx.x, d = threadIdx.x;
  size_t idx = (size_t)row * DD + d;
  float v = xin[idx] + (delta ? delta[idx] : 0.f);
  float s = v, s2 = v * v;
#pragma unroll
  for (int o = 1; o < 64; o <<= 1) {
    s += __shfl_xor(s, o, 64);
    s2 += __shfl_xor(s2, o, 64);
  }
  __shared__ float ws[4], ws2[4];
  int wid = d >> 6;
  if ((d & 63) == 0) { ws[wid] = s; ws2[wid] = s2; }
  __syncthreads();
  s = ws[0] + ws[1] + ws[2] + ws[3];
  s2 = ws2[0] + ws2[1] + ws2[2] + ws2[3];
  float m = s * (1.f / DD);
  float var = s2 * (1.f / DD) - m * m;
  float inv = rsqrtf(var + 1e-5f);
  out[idx] = (v - m) * inv * g[d] + bb[d];
}

// --------------------------------------------------------------------------- x init
__global__ __launch_bounds__(256) void k_init_x(const float* __restrict__ qe,
                                                const float* __restrict__ pt,
                                                float* __restrict__ x) {
  int r = blockIdx.x, d = threadIdx.x;
  int t = r % TT;
  x[(size_t)r * DD + d] = (t < NQRY) ? qe[t * DD + d] : pt[d];
}

// ------------------------- small attention (no bias): grid 64 = (b,h); thread = one query
// scores are provably small (|s| ~< 1): fixed-base softmax, no max subtraction needed.
__global__ __launch_bounds__(128) void k_attn_small(const float* __restrict__ q,
                                                    const float* __restrict__ k,
                                                    const float* __restrict__ v,
                                                    float* __restrict__ out,
                                                    int NK) {
  int bh = blockIdx.x;
  int b = bh >> 3, h = bh & 7;
  __shared__ float Ks[TT][HDIM];
  __shared__ float Vs[TT][HDIM];
  for (int i = threadIdx.x; i < NK * HDIM; i += 128) {
    int n = i >> 5, j = i & 31;
    Ks[n][j] = k[(size_t)(b * NK + n) * DD + h * HDIM + j];
    Vs[n][j] = v[(size_t)(b * NK + n) * DD + h * HDIM + j];
  }
  __syncthreads();
  int t = threadIdx.x;
  if (t >= TT) return;
  float qv[HDIM];
  const float* qp = q + (size_t)(b * TT + t) * DD + h * HDIM;
#pragma unroll
  for (int j = 0; j < HDIM; ++j) qv[j] = qp[j];
  const float sc = 0.17677669529663687f * 1.4426950408889634f;  // (1/sqrt(32)) * log2(e)
  float l = 0.f, acc[HDIM] = {};
  for (int n = 0; n < NK; ++n) {
    float s = 0.f;
#pragma unroll
    for (int j = 0; j < HDIM; ++j) s += qv[j] * Ks[n][j];
    float p = exp2f(s * sc);
    l += p;
#pragma unroll
    for (int j = 0; j < HDIM; ++j) acc[j] += p * Vs[n][j];
  }
  float inv = 1.f / l;
  float* op = out + (size_t)(b * TT + t) * DD + h * HDIM;
#pragma unroll
  for (int j = 0; j < HDIM; ++j) op[j] = acc[j] * inv;
}

// --------------------------------------------------------------- pos_q = x @ posW + posb
__global__ __launch_bounds__(128) void k_posq(const float* __restrict__ x,
                                              const float* __restrict__ Wp,
                                              const float* __restrict__ bp,
                                              float* __restrict__ pq) {
  int row = blockIdx.x;
  int c = threadIdx.x >> 5, lane = threadIdx.x & 31;
  if (c >= 3) return;
  float s = 0.f;
  for (int k = lane; k < DD; k += 32) s += x[(size_t)row * DD + k] * Wp[k * 3 + c];
#pragma unroll
  for (int o = 16; o; o >>= 1) s += __shfl_xor(s, o, 32);
  if (lane == 0) pq[row * 3 + c] = s + bp[c];
}

// ------------------- fused cross-attention with distance bias, chunked over keys.
// grid (64 bh, KCH); block 256 = 8 groups x 32 lanes (lane = head dim).
// Each group serves queries q = g + 8*qi (qi < 13). Fixed-base softmax (m = 0).
__global__ __launch_bounds__(256) void k_cross_attn(const float* __restrict__ q,
                                                    const float* __restrict__ K,
                                                    const float* __restrict__ V,
                                                    const float* __restrict__ pq,
                                                    const float* __restrict__ pm,
                                                    const float* __restrict__ beta_l,
                                                    float* __restrict__ pacc,
                                                    float* __restrict__ pl) {
  int bh = blockIdx.x, kc = blockIdx.y;
  int b = bh >> 3, h = bh & 7;
  float spb = log1pf(expf(beta_l[h]));  // softplus(beta)
  int g = threadIdx.x >> 5, j = threadIdx.x & 31;
  __shared__ float Ks[KTILE][HDIM];
  __shared__ float Vs[KTILE][HDIM];
  __shared__ float Ps[KTILE][4];

  float qv[NQI], l[NQI], ac[NQI], p0[NQI], p1[NQI], p2[NQI];
#pragma unroll
  for (int qi = 0; qi < NQI; ++qi) {
    int qq = g + 8 * qi;
    bool ok = qq < TT;
    size_t xr = (size_t)(b * TT + (ok ? qq : 0));
    qv[qi] = ok ? q[xr * DD + h * HDIM + j] : 0.f;
    p0[qi] = ok ? pq[xr * 3 + 0] : 0.f;
    p1[qi] = ok ? pq[xr * 3 + 1] : 0.f;
    p2[qi] = ok ? pq[xr * 3 + 2] : 0.f;
    l[qi] = 0.f;
    ac[qi] = 0.f;
  }
  const float sc = 0.17677669529663687f;
  const float L2E = 1.4426950408889634f;

  for (int n0 = kc * KPC; n0 < kc * KPC + KPC; n0 += KTILE) {
    __syncthreads();
    for (int i = threadIdx.x; i < KTILE * HDIM; i += 256) {
      int n = i >> 5, jj = i & 31;
      size_t kr = (size_t)(b * NN + n0 + n) * DD + h * HDIM + jj;
      Ks[n][jj] = K[kr];
      Vs[n][jj] = V[kr];
    }
    for (int i = threadIdx.x; i < KTILE * 3; i += 256) {
      int n = i / 3, c = i % 3;
      Ps[n][c] = pm[(size_t)(b * NN + n0 + n) * 3 + c];
    }
    __syncthreads();
    for (int n = 0; n < KTILE; ++n) {
      float kj = Ks[n][j];
      float vj = Vs[n][j];
      float mx = Ps[n][0], my = Ps[n][1], mz = Ps[n][2];
#pragma unroll
      for (int qi = 0; qi < NQI; ++qi) {
        float part = qv[qi] * kj;
        part += __shfl_xor(part, 1, 32);
        part += __shfl_xor(part, 2, 32);
        part += __shfl_xor(part, 4, 32);
        part += __shfl_xor(part, 8, 32);
        part += __shfl_xor(part, 16, 32);
        float dx = p0[qi] - mx, dy = p1[qi] - my, dz = p2[qi] - mz;
        float d2 = dx * dx + dy * dy + dz * dz;
        float s = part * sc - spb * d2;
        float p = exp2f(s * L2E);
        l[qi] += p;
        ac[qi] += p * vj;
      }
    }
  }
#pragma unroll
  for (int qi = 0; qi < NQI; ++qi) {
    int qq = g + 8 * qi;
    if (qq < TT) {
      pacc[(((size_t)kc * 64 + bh) * TT + qq) * HDIM + j] = ac[qi];
      if (j == 0) pl[((size_t)kc * 64 + bh) * TT + qq] = l[qi];
    }
  }
}

// ---------------------------------------- merge key-chunk partials (fixed base: plain sums)
__global__ __launch_bounds__(256) void k_cross_merge(const float* __restrict__ pacc,
                                                     const float* __restrict__ pl,
                                                     float* __restrict__ out) {
  int bh = blockIdx.x;
  int b = bh >> 3, h = bh & 7;
  int q8 = blockIdx.y * 8 + (threadIdx.x >> 5);
  int j = threadIdx.x & 31;
  if (q8 >= TT) return;
  float sa = 0.f, sl = 0.f;
  for (int kc = 0; kc < KCH; ++kc) {
    sa += pacc[(((size_t)kc * 64 + bh) * TT + q8) * HDIM + j];
    sl += pl[((size_t)kc * 64 + bh) * TT + q8];
  }
  out[((size_t)(b * TT + q8)) * DD + h * HDIM + j] = sa / sl;
}

// -------------------------------------------------------------------- epilogue helpers
__global__ __launch_bounds__(256) void k_copy_hs(const float* __restrict__ x,
                                                 float* __restrict__ out) {
  int r = blockIdx.x, d = threadIdx.x;
  int b = r / NQRY, qq = r % NQRY;
  out[(size_t)r * DD + d] = x[((size_t)(b * TT + qq)) * DD + d];
}

__global__ __launch_bounds__(256) void k_gather_pres(const float* __restrict__ x,
                                                     float* __restrict__ pres) {
  int b = blockIdx.x, d = threadIdx.x;
  pres[(size_t)b * DD + d] = x[((size_t)(b * TT + NQRY)) * DD + d];
}

__global__ __launch_bounds__(256) void k_logit(const float* __restrict__ h2,
                                               const float* __restrict__ W3,
                                               const float* __restrict__ b3,
                                               float* __restrict__ out) {
  int r = threadIdx.x >> 5, lane = threadIdx.x & 31;
  float s = 0.f;
  for (int k = lane; k < DD; k += 32) s += h2[r * DD + k] * W3[k];
#pragma unroll
  for (int o = 16; o; o >>= 1) s += __shfl_xor(s, o, 32);
  if (lane == 0) out[r] = s + b3[0];
}

// =======================================================================================
extern "C" void kernel_launch(void* const* d_in, const int* in_sizes, int n_in,
                              void* d_out, int out_size, void* d_ws, size_t ws_size,
                              hipStream_t stream) {
  (void)in_sizes; (void)n_in; (void)out_size; (void)ws_size;
  auto F = [&](int i) { return (const float*)d_in[i]; };
  const float* img   = F(0);
  const float* txtf  = F(1);
  const float* pm    = F(2);
  const float* qe    = F(3);
  const float* ptok  = F(4);
  const float* tpW   = F(5);
  const float* tpb   = F(6);
  const float* tWq   = F(7);  const float* tbq = F(8);
  const float* tWk   = F(9);  const float* tbk = F(10);
  const float* tWv   = F(11); const float* tbv = F(12);
  const float* tWo   = F(13); const float* tbo = F(14);
  const float* tlng  = F(15); const float* tlnb = F(16);
  const float* wpeW  = F(17); const float* wpeb = F(18);
  const float* saWq  = F(19); const float* sabq = F(20);
  const float* saWk  = F(21); const float* sabk = F(22);
  const float* saWv  = F(23); const float* sabv = F(24);
  const float* saWo  = F(25); const float* sabo = F(26);
  const float* caWq  = F(27); const float* cabq = F(28);
  const float* caWk  = F(29); const float* cabk = F(30);
  const float* caWv  = F(31); const float* cabv = F(32);
  const float* caWo  = F(33); const float* cabo = F(34);
  const float* fW1   = F(35); const float* fb1 = F(36);
  const float* fW2   = F(37); const float* fb2 = F(38);
  const float* ln1g  = F(39); const float* ln1b = F(40);
  const float* ln2g  = F(41); const float* ln2b = F(42);
  const float* ln3g  = F(43); const float* ln3b = F(44);
  const float* posW  = F(45); const float* posb = F(46);
  const float* beta  = F(47);
  const float* fing  = F(48); const float* finb = F(49);
  const float* pW1   = F(50); const float* pb1 = F(51);
  const float* pW2   = F(52); const float* pb2 = F(53);
  const float* pW3   = F(54); const float* pb3 = F(55);

  char* wp = (char*)d_ws;
  auto alloc = [&](size_t nfloats) {
    float* p = (float*)wp;
    wp += (nfloats * 4 + 255) & ~(size_t)255;
    return p;
  };
  float* mem  = alloc((size_t)BNN * DD);
  float* Kb   = alloc((size_t)BNN * DD);
  float* Vb   = alloc((size_t)BNN * DD);
  float* x    = alloc((size_t)MM * DD);
  float* tA   = alloc((size_t)MM * DD);
  float* tB   = alloc((size_t)MM * DD);
  float* tC   = alloc((size_t)MM * DD);
  float* tD   = alloc((size_t)MM * DD);
  float* hb   = alloc((size_t)MM * FFD);
  float* txt  = alloc((size_t)BB * NTXT * DD);
  float* tK   = alloc((size_t)BB * NTXT * DD);
  float* tV   = alloc((size_t)BB * NTXT * DD);
  float* pacc = alloc((size_t)KCH * 64 * TT * HDIM);
  float* pl   = alloc((size_t)KCH * 64 * TT);
  float* posq = alloc((size_t)MM * 3);
  float* pres = alloc((size_t)BB * DD);
  float* ph1  = alloc((size_t)BB * DD);
  float* ph2  = alloc((size_t)BB * DD);

  // ---- phase 0: mem, text projections, x init, text cross-attn block
  k_mem<<<BNN / 4, 256, 0, stream>>>(img, pm, wpeW, wpeb, mem);
  k_linear256<<<32, 256, 0, stream>>>(txtf, tpW, tpb, txt, BB * NTXT, 0);
  k_linear256<<<32, 256, 0, stream>>>(txt, tWk, tbk, tK, BB * NTXT, 0);
  k_linear256<<<32, 256, 0, stream>>>(txt, tWv, tbv, tV, BB * NTXT, 0);
  k_init_x<<<MM, 256, 0, stream>>>(qe, ptok, x);
  k_linear256<<<101, 256, 0, stream>>>(x, tWq, tbq, tA, MM, 0);
  k_attn_small<<<64, 128, 0, stream>>>(tA, tK, tV, tB, NTXT);
  k_linear256<<<101, 256, 0, stream>>>(tB, tWo, tbo, tC, MM, 0);
  k_add_ln<<<MM, 256, 0, stream>>>(x, tC, tlng, tlnb, x);

  for (int i = 0; i < NLAY; ++i) {
    size_t wo = (size_t)i * DD * DD;
    // self-attention
    k_linear256<<<101, 256, 0, stream>>>(x, saWq + wo, sabq + i * DD, tA, MM, 0);
    k_linear256<<<101, 256, 0, stream>>>(x, saWk + wo, sabk + i * DD, tB, MM, 0);
    k_linear256<<<101, 256, 0, stream>>>(x, saWv + wo, sabv + i * DD, tC, MM, 0);
    k_attn_small<<<64, 128, 0, stream>>>(tA, tB, tC, tD, TT);
    k_linear256<<<101, 256, 0, stream>>>(tD, saWo + wo, sabo + i * DD, tA, MM, 0);
    k_add_ln<<<MM, 256, 0, stream>>>(x, tA, ln1g + i * DD, ln1b + i * DD, x);
    // positional query + cross-attention
    k_posq<<<MM, 128, 0, stream>>>(x, posW + (size_t)i * DD * 3, posb + i * 3, posq);
    k_linear256<<<101, 256, 0, stream>>>(x, caWq + wo, cabq + i * DD, tA, MM, 0);
    dim3 gkv(BNN / 64, DD / 64);
    k_gemm<<<gkv, 256, 0, stream>>>(mem, caWk + wo, cabk + i * DD, Kb, BNN, DD, DD, 0);
    k_gemm<<<gkv, 256, 0, stream>>>(mem, caWv + wo, cabv + i * DD, Vb, BNN, DD, DD, 0);
    k_cross_attn<<<dim3(64, KCH), 256, 0, stream>>>(tA, Kb, Vb, posq, pm,
                                                    beta + i * NH, pacc, pl);
    k_cross_merge<<<dim3(64, 13), 256, 0, stream>>>(pacc, pl, tB);
    k_linear256<<<101, 256, 0, stream>>>(tB, caWo + wo, cabo + i * DD, tC, MM, 0);
    k_add_ln<<<MM, 256, 0, stream>>>(x, tC, ln2g + i * DD, ln2b + i * DD, x);
    // FFN
    k_gemm<<<dim3(13, FFD / 64), 256, 0, stream>>>(x, fW1 + (size_t)i * DD * FFD,
                                                   fb1 + i * FFD, hb, MM, DD, FFD, 1);
    k_gemm<<<dim3(13, DD / 64), 256, 0, stream>>>(hb, fW2 + (size_t)i * FFD * DD,
                                                  fb2 + i * DD, tA, MM, FFD, DD, 0);
    k_add_ln<<<MM, 256, 0, stream>>>(x, tA, ln3g + i * DD, ln3b + i * DD, x);
  }

  // ---- epilogue
  k_add_ln<<<MM, 256, 0, stream>>>(x, nullptr, fing, finb, x);
  k_copy_hs<<<BB * NQRY, 256, 0, stream>>>(x, (float*)d_out);
  k_gather_pres<<<BB, 256, 0, stream>>>(x, pres);
  k_linear256<<<1, 256, 0, stream>>>(pres, pW1, pb1, ph1, BB, 1);
  k_linear256<<<1, 256, 0, stream>>>(ph1, pW2, pb2, ph2, BB, 1);
  k_logit<<<1, 256, 0, stream>>>(ph2, pW3, pb3, (float*)d_out + (size_t)BB * NQRY * DD);
}

// Round 2
// 1831.330 us; speedup vs baseline: 6.8530x; 6.8530x over previous
//
#include <hip/hip_runtime.h>
#include <math.h>

#define DD 256
#define NH 8
#define HDIM 32
#define NLAY 6
#define NQRY 100
#define TT 101
#define BB 8
#define NN 4096
#define NTXT 32
#define FFD 2048
#define MM (BB*TT)      // 808
#define MMP (896)       // padded rows for GEMM tiles
#define BNN (BB*NN)     // 32768
#define KC 8            // key chunks for cross-attn
#define KPC (NN/KC)     // 512

typedef __bf16 bf16x8 __attribute__((ext_vector_type(8)));
typedef float f32x4v __attribute__((ext_vector_type(4)));
typedef unsigned int u32x4 __attribute__((ext_vector_type(4)));
typedef unsigned int u32x2 __attribute__((ext_vector_type(2)));

__device__ __forceinline__ ushort f2b(float f) {
  unsigned u = __builtin_bit_cast(unsigned, f);
  u += 0x7FFF + ((u >> 16) & 1);
  return (ushort)(u >> 16);
}
__device__ __forceinline__ unsigned pk2(float lo, float hi) {
  return (unsigned)f2b(lo) | ((unsigned)f2b(hi) << 16);
}
__device__ __forceinline__ f32x4v mfma16(bf16x8 a, bf16x8 b, f32x4v c) {
  return __builtin_amdgcn_mfma_f32_16x16x32_bf16(a, b, c, 0, 0, 0);
}

// ------------------------------------------------- mem = bf16(img + enc @ wpeW + wpeb)
__global__ __launch_bounds__(256) void k_mem(const float* __restrict__ img,
                                             const float* __restrict__ pm,
                                             const float* __restrict__ wpeW,
                                             const float* __restrict__ wpeb,
                                             ushort* __restrict__ memb) {
  int r0 = blockIdx.x * 4;
  __shared__ float enc[4][60];
  int t = threadIdx.x;
  if (t < 240) {
    int r = t / 60, i = t % 60;
    int c = i / 20, jj = i % 20;
    float p = pm[(size_t)(r0 + r) * 3 + c];
    float f = (float)(1 << (jj % 10));
    float a = p * f;
    enc[r][i] = (jj < 10) ? sinf(a) : cosf(a);
  }
  __syncthreads();
  int d = t;
  float bv = wpeb[d];
  float a0 = bv + img[(size_t)(r0 + 0) * DD + d];
  float a1 = bv + img[(size_t)(r0 + 1) * DD + d];
  float a2 = bv + img[(size_t)(r0 + 2) * DD + d];
  float a3 = bv + img[(size_t)(r0 + 3) * DD + d];
  for (int i = 0; i < 60; ++i) {
    float w = wpeW[i * DD + d];
    a0 += enc[0][i] * w;
    a1 += enc[1][i] * w;
    a2 += enc[2][i] * w;
    a3 += enc[3][i] * w;
  }
  memb[(size_t)(r0 + 0) * DD + d] = f2b(a0);
  memb[(size_t)(r0 + 1) * DD + d] = f2b(a1);
  memb[(size_t)(r0 + 2) * DD + d] = f2b(a2);
  memb[(size_t)(r0 + 3) * DD + d] = f2b(a3);
}

// ------------------------------------------------- y = act(x @ W + b), K=N=256 (f32)
__global__ __launch_bounds__(256) void k_linear256(const float* __restrict__ x,
                                                   const float* __restrict__ W,
                                                   const float* __restrict__ b,
                                                   float* __restrict__ y,
                                                   int Mr, int relu) {
  int r0 = blockIdx.x * 8;
  int d = threadIdx.x;
  __shared__ float xs[8][DD];
  for (int i = threadIdx.x; i < 8 * DD; i += 256) {
    int r = i >> 8, k = i & 255;
    xs[r][k] = (r0 + r < Mr) ? x[(size_t)(r0 + r) * DD + k] : 0.f;
  }
  __syncthreads();
  float acc[8] = {};
  for (int k = 0; k < DD; ++k) {
    float w = W[k * DD + d];
#pragma unroll
    for (int r = 0; r < 8; ++r) acc[r] += xs[r][k] * w;
  }
  float bb = b[d];
#pragma unroll
  for (int r = 0; r < 8; ++r) {
    if (r0 + r < Mr) {
      float v = acc[r] + bb;
      if (relu) v = fmaxf(v, 0.f);
      y[(size_t)(r0 + r) * DD + d] = v;
    }
  }
}

// --------------------------------------- transpose+convert: in f32 [K][N] -> out bf16 [N][K]
__global__ __launch_bounds__(256) void k_t2b(const float* __restrict__ in,
                                             ushort* __restrict__ out, int K, int N) {
  __shared__ ushort T[64][72];
  int k0 = blockIdx.x * 64, n0 = blockIdx.y * 64;
  int t = threadIdx.x;
  int kk = t >> 4, nn4 = (t & 15) * 4;
#pragma unroll
  for (int p = 0; p < 4; ++p) {
    int krow = kk + p * 16;
    float4 v = *(const float4*)(in + (size_t)(k0 + krow) * N + n0 + nn4);
    T[nn4 + 0][krow] = f2b(v.x);
    T[nn4 + 1][krow] = f2b(v.y);
    T[nn4 + 2][krow] = f2b(v.z);
    T[nn4 + 3][krow] = f2b(v.w);
  }
  __syncthreads();
  int nn = t >> 3, kk8 = (t & 7) * 8;
#pragma unroll
  for (int p = 0; p < 2; ++p) {
    int nrow = nn + p * 32;
    u32x4 v = *(const u32x4*)(&T[nrow][kk8]);
    *(u32x4*)(out + (size_t)(n0 + nrow) * K + k0 + kk8) = v;
  }
}

// ------------------------------------------------------------ flat f32 -> bf16 convert
__global__ __launch_bounds__(256) void k_f2b(const float* __restrict__ in,
                                             ushort* __restrict__ out, int n) {
  int i = (blockIdx.x * 256 + threadIdx.x) * 4;
  if (i + 3 < n) {
    float4 v = *(const float4*)(in + i);
    out[i + 0] = f2b(v.x);
    out[i + 1] = f2b(v.y);
    out[i + 2] = f2b(v.z);
    out[i + 3] = f2b(v.w);
  }
}

// ------------------------------------------------------------ pm4 = (x, y, z, |p|^2)
__global__ __launch_bounds__(256) void k_pm4(const float* __restrict__ pm,
                                             float4* __restrict__ pm4) {
  int i = blockIdx.x * 256 + threadIdx.x;
  float x = pm[(size_t)i * 3 + 0];
  float y = pm[(size_t)i * 3 + 1];
  float z = pm[(size_t)i * 3 + 2];
  float4 v;
  v.x = x; v.y = y; v.z = z; v.w = x * x + y * y + z * z;
  pm4[i] = v;
}

// ------------------- bf16 MFMA GEMM: C = act(A[M,K] @ Bt[N,K]^T + bias)
// tile 128x64, BK=64; OM: 0=f32 out, 1=bf16 out, 2=bf16+relu out, 3=V^T-per-head bf16 out
template <int OM>
__global__ __launch_bounds__(256) void k_gemm_bf(const ushort* __restrict__ A,
                                                 const ushort* __restrict__ Bt,
                                                 const float* __restrict__ bias,
                                                 void* __restrict__ C,
                                                 int M, int N, int K) {
  __shared__ __align__(16) char AsB[16384];  // 128 rows x 128B (swizzled)
  __shared__ __align__(16) char BsB[8192];   // 64 rows x 128B (swizzled)
  int m0 = blockIdx.x * 128, n0 = blockIdx.y * 64;
  int t = threadIdx.x, w = t >> 6, l = t & 63, lq = l & 15, lg = l >> 4;
  int acol = (t & 7) * 8;  // ushort units
  f32x4v acc[2][4] = {};

  for (int k0 = 0; k0 < K; k0 += 64) {
    __syncthreads();
#pragma unroll
    for (int p = 0; p < 4; ++p) {
      int row = (t >> 3) + p * 32;
      u32x4 v = *(const u32x4*)(A + (size_t)(m0 + row) * K + k0 + acol);
      *(u32x4*)(AsB + row * 128 + ((acol * 2) ^ ((row & 7) << 4))) = v;
    }
#pragma unroll
    for (int p = 0; p < 2; ++p) {
      int row = (t >> 3) + p * 32;
      u32x4 v = *(const u32x4*)(Bt + (size_t)(n0 + row) * K + k0 + acol);
      *(u32x4*)(BsB + row * 128 + ((acol * 2) ^ ((row & 7) << 4))) = v;
    }
    __syncthreads();
#pragma unroll
    for (int ks = 0; ks < 2; ++ks) {
      bf16x8 af[2], bfr[4];
#pragma unroll
      for (int mt = 0; mt < 2; ++mt) {
        int row = w * 32 + mt * 16 + lq;
        int kb = ks * 64 + lg * 16;
        af[mt] = __builtin_bit_cast(
            bf16x8, *(const u32x4*)(AsB + row * 128 + (kb ^ ((row & 7) << 4))));
      }
#pragma unroll
      for (int nt = 0; nt < 4; ++nt) {
        int row = nt * 16 + lq;
        int kb = ks * 64 + lg * 16;
        bfr[nt] = __builtin_bit_cast(
            bf16x8, *(const u32x4*)(BsB + row * 128 + (kb ^ ((row & 7) << 4))));
      }
#pragma unroll
      for (int mt = 0; mt < 2; ++mt)
#pragma unroll
        for (int nt = 0; nt < 4; ++nt) acc[mt][nt] = mfma16(af[mt], bfr[nt], acc[mt][nt]);
    }
  }

#pragma unroll
  for (int nt = 0; nt < 4; ++nt) {
    int n = n0 + nt * 16 + lq;
    float bv = bias[n];
#pragma unroll
    for (int mt = 0; mt < 2; ++mt) {
      int rowg = m0 + w * 32 + mt * 16 + lg * 4;
      f32x4v a = acc[mt][nt];
      a[0] += bv; a[1] += bv; a[2] += bv; a[3] += bv;
      if (OM == 2) {
        a[0] = fmaxf(a[0], 0.f); a[1] = fmaxf(a[1], 0.f);
        a[2] = fmaxf(a[2], 0.f); a[3] = fmaxf(a[3], 0.f);
      }
      if (OM == 0) {
        float* Cf = (float*)C;
#pragma unroll
        for (int r = 0; r < 4; ++r)
          if (rowg + r < M) Cf[(size_t)(rowg + r) * N + n] = a[r];
      } else if (OM == 1 || OM == 2) {
        ushort* Cb = (ushort*)C;
#pragma unroll
        for (int r = 0; r < 4; ++r)
          if (rowg + r < M) Cb[(size_t)(rowg + r) * N + n] = f2b(a[r]);
      } else {
        // V^T per head: out[((b*8+h)*32+d)][key], key = rowg&4095, b = rowg>>12
        ushort* Vt = (ushort*)C;
        int b = rowg >> 12, key = rowg & 4095;
        int h = n >> 5, d = n & 31;
        u32x2 pv;
        pv[0] = pk2(a[0], a[1]);
        pv[1] = pk2(a[2], a[3]);
        *(u32x2*)(Vt + ((size_t)((b * 8 + h) * 32 + d) * 4096 + key)) = pv;
      }
    }
  }
}

// ---------------------------------------------------------- out = LN(xin (+delta)) * g + b
__global__ __launch_bounds__(256) void k_add_ln(const float* __restrict__ xin,
                                                const float* __restrict__ delta,
                                                const float* __restrict__ g,
                                                const float* __restrict__ bb,
                                                float* __restrict__ out) {
  int row = blockIdx.x, d = threadIdx.x;
  size_t idx = (size_t)row * DD + d;
  float v = xin[idx] + (delta ? delta[idx] : 0.f);
  float s = v, s2 = v * v;
#pragma unroll
  for (int o = 1; o < 64; o <<= 1) {
    s += __shfl_xor(s, o, 64);
    s2 += __shfl_xor(s2, o, 64);
  }
  __shared__ float ws[4], ws2[4];
  int wid = d >> 6;
  if ((d & 63) == 0) { ws[wid] = s; ws2[wid] = s2; }
  __syncthreads();
  s = ws[0] + ws[1] + ws[2] + ws[3];
  s2 = ws2[0] + ws2[1] + ws2[2] + ws2[3];
  float m = s * (1.f / DD);
  float var = s2 * (1.f / DD) - m * m;
  float inv = rsqrtf(var + 1e-5f);
  out[idx] = (v - m) * inv * g[d] + bb[d];
}

// --------------------------------------------------------------------------- x init
__global__ __launch_bounds__(256) void k_init_x(const float* __restrict__ qe,
                                                const float* __restrict__ pt,
                                                float* __restrict__ x) {
  int r = blockIdx.x, d = threadIdx.x;
  int t = r % TT;
  x[(size_t)r * DD + d] = (t < NQRY) ? qe[t * DD + d] : pt[d];
}

// ------------------------- small attention (no bias), f32, fixed-base softmax
__global__ __launch_bounds__(128) void k_attn_small(const float* __restrict__ q,
                                                    const float* __restrict__ k,
                                                    const float* __restrict__ v,
                                                    float* __restrict__ out,
                                                    int NK) {
  int bh = blockIdx.x;
  int b = bh >> 3, h = bh & 7;
  __shared__ float Ks[TT][HDIM];
  __shared__ float Vs[TT][HDIM];
  for (int i = threadIdx.x; i < NK * HDIM; i += 128) {
    int n = i >> 5, j = i & 31;
    Ks[n][j] = k[(size_t)(b * NK + n) * DD + h * HDIM + j];
    Vs[n][j] = v[(size_t)(b * NK + n) * DD + h * HDIM + j];
  }
  __syncthreads();
  int t = threadIdx.x;
  if (t >= TT) return;
  float qv[HDIM];
  const float* qp = q + (size_t)(b * TT + t) * DD + h * HDIM;
#pragma unroll
  for (int j = 0; j < HDIM; ++j) qv[j] = qp[j];
  const float sc = 0.17677669529663687f * 1.4426950408889634f;
  float l = 0.f, acc[HDIM] = {};
  for (int n = 0; n < NK; ++n) {
    float s = 0.f;
#pragma unroll
    for (int j = 0; j < HDIM; ++j) s += qv[j] * Ks[n][j];
    float p = exp2f(s * sc);
    l += p;
#pragma unroll
    for (int j = 0; j < HDIM; ++j) acc[j] += p * Vs[n][j];
  }
  float inv = 1.f / l;
  float* op = out + (size_t)(b * TT + t) * DD + h * HDIM;
#pragma unroll
  for (int j = 0; j < HDIM; ++j) op[j] = acc[j] * inv;
}

// --------------------------------------------------------------- pos_q = x @ posW + posb
__global__ __launch_bounds__(128) void k_posq(const float* __restrict__ x,
                                              const float* __restrict__ Wp,
                                              const float* __restrict__ bp,
                                              float* __restrict__ pq) {
  int row = blockIdx.x;
  int c = threadIdx.x >> 5, lane = threadIdx.x & 31;
  if (c >= 3) return;
  float s = 0.f;
  for (int k = lane; k < DD; k += 32) s += x[(size_t)row * DD + k] * Wp[k * 3 + c];
#pragma unroll
  for (int o = 16; o; o >>= 1) s += __shfl_xor(s, o, 32);
  if (lane == 0) pq[row * 3 + c] = s + bp[c];
}

// ------------------- MFMA flash cross-attention with distance bias.
// grid (64 bh, KC); block 256 = 4 waves; wave handles 2 query-tiles of 16.
// swapped QK^T: S^T = mfma(K, Q) -> C col=query,row=key; PV: O^T = mfma(Vt, P).
__global__ __launch_bounds__(256) void k_cross_mfma(
    const float* __restrict__ Q,      // [MM][256] f32 (unscaled q projection)
    const ushort* __restrict__ Kb,    // [BNN][256] bf16
    const ushort* __restrict__ Vt,    // [64 bh][32 d][4096 key] bf16
    const float* __restrict__ posq,   // [MM][3]
    const float4* __restrict__ pm4,   // [BNN] (x,y,z,|p|^2)
    const float* __restrict__ betaL,  // [8]
    float* __restrict__ pacc, float* __restrict__ pl) {
  int bh = blockIdx.x, kc = blockIdx.y;
  int b = bh >> 3, h = bh & 7;
  int t = threadIdx.x, w = t >> 6, l = t & 63, lq = l & 15, lg = l >> 4;
  const float L2E = 1.4426950408889634f;
  const float c1 = 0.17677669529663687f * L2E;
  float spb = log1pf(expf(betaL[h]));
  float cb = spb * L2E;

  __shared__ float4 pm4s[KPC];
  __shared__ ushort Plds[4][2][16][40];  // per-wave, per-qtile P (padded rows)

  int kbase = b * NN + kc * KPC;
  for (int i = t; i < KPC; i += 256) pm4s[i] = pm4[kbase + i];
  __syncthreads();

  const f32x4v Z = {0.f, 0.f, 0.f, 0.f};
  bf16x8 qfb[2];
  float a0[2], px[2], py[2], pz[2];
  f32x4v oacc[2][2] = {};
  float lsum[2] = {0.f, 0.f};

#pragma unroll
  for (int qi = 0; qi < 2; ++qi) {
    int qt = w * 2 + qi;
    int qidx = qt * 16 + lq;
    int qc = qidx < TT ? qidx : TT - 1;
    size_t xr = (size_t)(b * TT + qc);
    const float* qp = Q + xr * 256 + h * 32 + lg * 8;
    float4 q0 = *(const float4*)qp;
    float4 q1 = *(const float4*)(qp + 4);
    u32x4 qv;
    qv[0] = pk2(q0.x * c1, q0.y * c1);
    qv[1] = pk2(q0.z * c1, q0.w * c1);
    qv[2] = pk2(q1.x * c1, q1.y * c1);
    qv[3] = pk2(q1.z * c1, q1.w * c1);
    qfb[qi] = __builtin_bit_cast(bf16x8, qv);
    float qx = posq[xr * 3 + 0], qy = posq[xr * 3 + 1], qz = posq[xr * 3 + 2];
    a0[qi] = -cb * (qx * qx + qy * qy + qz * qz);
    px[qi] = 2.f * cb * qx;
    py[qi] = 2.f * cb * qy;
    pz[qi] = 2.f * cb * qz;
  }

  for (int kk = 0; kk < KPC; kk += 32) {
    bf16x8 kf[2], vf[2];
#pragma unroll
    for (int t2 = 0; t2 < 2; ++t2)
      kf[t2] = __builtin_bit_cast(
          bf16x8, *(const u32x4*)(Kb + (size_t)(kbase + kk + t2 * 16 + lq) * 256 +
                                  h * 32 + lg * 8));
#pragma unroll
    for (int dt = 0; dt < 2; ++dt)
      vf[dt] = __builtin_bit_cast(
          bf16x8, *(const u32x4*)(Vt + (size_t)(bh * 32 + dt * 16 + lq) * 4096 +
                                  kc * KPC + kk + lg * 8));
    // per-key bias pieces (shared across the 2 query tiles)
    float bx[2][4], by[2][4], bz[2][4], b0[2][4];
#pragma unroll
    for (int t2 = 0; t2 < 2; ++t2)
#pragma unroll
      for (int r = 0; r < 4; ++r) {
        float4 pv = pm4s[kk + t2 * 16 + lg * 4 + r];
        bx[t2][r] = pv.x; by[t2][r] = pv.y; bz[t2][r] = pv.z;
        b0[t2][r] = cb * pv.w;
      }
#pragma unroll
    for (int qi = 0; qi < 2; ++qi) {
      f32x4v s0 = mfma16(kf[0], qfb[qi], Z);
      f32x4v s1 = mfma16(kf[1], qfb[qi], Z);
      float p[2][4];
#pragma unroll
      for (int t2 = 0; t2 < 2; ++t2) {
#pragma unroll
        for (int r = 0; r < 4; ++r) {
          float sv = (t2 == 0) ? s0[r] : s1[r];
          float bias = fmaf(px[qi], bx[t2][r],
                       fmaf(py[qi], by[t2][r],
                       fmaf(pz[qi], bz[t2][r], a0[qi] - b0[t2][r])));
          p[t2][r] = exp2f(sv + bias);
        }
        lsum[qi] += (p[t2][0] + p[t2][1]) + (p[t2][2] + p[t2][3]);
      }
      u32x2 w0, w1;
      w0[0] = pk2(p[0][0], p[0][1]);
      w0[1] = pk2(p[0][2], p[0][3]);
      w1[0] = pk2(p[1][0], p[1][1]);
      w1[1] = pk2(p[1][2], p[1][3]);
      *(u32x2*)(&Plds[w][qi][lq][lg * 4]) = w0;
      *(u32x2*)(&Plds[w][qi][lq][16 + lg * 4]) = w1;
      bf16x8 pf = __builtin_bit_cast(bf16x8, *(const u32x4*)(&Plds[w][qi][lq][lg * 8]));
      oacc[qi][0] = mfma16(vf[0], pf, oacc[qi][0]);
      oacc[qi][1] = mfma16(vf[1], pf, oacc[qi][1]);
    }
  }

#pragma unroll
  for (int qi = 0; qi < 2; ++qi) {
    float lv = lsum[qi];
    lv += __shfl_xor(lv, 16, 64);
    lv += __shfl_xor(lv, 32, 64);
    int qt = w * 2 + qi;
    int qidx = qt * 16 + lq;
    if (qidx < TT) {
      size_t o = ((size_t)(kc * 64 + bh) * TT + qidx) * 32;
#pragma unroll
      for (int dt = 0; dt < 2; ++dt) {
        f32x4v a = oacc[qi][dt];
        float4 st;
        st.x = a[0]; st.y = a[1]; st.z = a[2]; st.w = a[3];
        *(float4*)(pacc + o + dt * 16 + lg * 4) = st;
      }
      if (lg == 0) pl[(size_t)(kc * 64 + bh) * TT + qidx] = lv;
    }
  }
}

// ---------------------------------------- merge key-chunk partials (fixed base: plain sums)
__global__ __launch_bounds__(256) void k_cross_merge(const float* __restrict__ pacc,
                                                     const float* __restrict__ pl,
                                                     float* __restrict__ out) {
  int bh = blockIdx.x;
  int b = bh >> 3, h = bh & 7;
  int q8 = blockIdx.y * 8 + (threadIdx.x >> 5);
  int j = threadIdx.x & 31;
  if (q8 >= TT) return;
  float sa = 0.f, sl = 0.f;
  for (int kc = 0; kc < KC; ++kc) {
    sa += pacc[(((size_t)kc * 64 + bh) * TT + q8) * HDIM + j];
    sl += pl[((size_t)kc * 64 + bh) * TT + q8];
  }
  out[((size_t)(b * TT + q8)) * DD + h * HDIM + j] = sa / sl;
}

// -------------------------------------------------------------------- epilogue helpers
__global__ __launch_bounds__(256) void k_copy_hs(const float* __restrict__ x,
                                                 float* __restrict__ out) {
  int r = blockIdx.x, d = threadIdx.x;
  int b = r / NQRY, qq = r % NQRY;
  out[(size_t)r * DD + d] = x[((size_t)(b * TT + qq)) * DD + d];
}

__global__ __launch_bounds__(256) void k_gather_pres(const float* __restrict__ x,
                                                     float* __restrict__ pres) {
  int b = blockIdx.x, d = threadIdx.x;
  pres[(size_t)b * DD + d] = x[((size_t)(b * TT + NQRY)) * DD + d];
}

__global__ __launch_bounds__(256) void k_logit(const float* __restrict__ h2,
                                               const float* __restrict__ W3,
                                               const float* __restrict__ b3,
                                               float* __restrict__ out) {
  int r = threadIdx.x >> 5, lane = threadIdx.x & 31;
  float s = 0.f;
  for (int k = lane; k < DD; k += 32) s += h2[r * DD + k] * W3[k];
#pragma unroll
  for (int o = 16; o; o >>= 1) s += __shfl_xor(s, o, 32);
  if (lane == 0) out[r] = s + b3[0];
}

// =======================================================================================
extern "C" void kernel_launch(void* const* d_in, const int* in_sizes, int n_in,
                              void* d_out, int out_size, void* d_ws, size_t ws_size,
                              hipStream_t stream) {
  (void)in_sizes; (void)n_in; (void)out_size; (void)ws_size;
  auto F = [&](int i) { return (const float*)d_in[i]; };
  const float* img   = F(0);
  const float* txtf  = F(1);
  const float* pm    = F(2);
  const float* qe    = F(3);
  const float* ptok  = F(4);
  const float* tpW   = F(5);
  const float* tpb   = F(6);
  const float* tWq   = F(7);  const float* tbq = F(8);
  const float* tWk   = F(9);  const float* tbk = F(10);
  const float* tWv   = F(11); const float* tbv = F(12);
  const float* tWo   = F(13); const float* tbo = F(14);
  const float* tlng  = F(15); const float* tlnb = F(16);
  const float* wpeW  = F(17); const float* wpeb = F(18);
  const float* saWq  = F(19); const float* sabq = F(20);
  const float* saWk  = F(21); const float* sabk = F(22);
  const float* saWv  = F(23); const float* sabv = F(24);
  const float* saWo  = F(25); const float* sabo = F(26);
  const float* caWq  = F(27); const float* cabq = F(28);
  const float* caWk  = F(29); const float* cabk = F(30);
  const float* caWv  = F(31); const float* cabv = F(32);
  const float* caWo  = F(33); const float* cabo = F(34);
  const float* fW1   = F(35); const float* fb1 = F(36);
  const float* fW2   = F(37); const float* fb2 = F(38);
  const float* ln1g  = F(39); const float* ln1b = F(40);
  const float* ln2g  = F(41); const float* ln2b = F(42);
  const float* ln3g  = F(43); const float* ln3b = F(44);
  const float* posW  = F(45); const float* posb = F(46);
  const float* beta  = F(47);
  const float* fing  = F(48); const float* finb = F(49);
  const float* pW1   = F(50); const float* pb1 = F(51);
  const float* pW2   = F(52); const float* pb2 = F(53);
  const float* pW3   = F(54); const float* pb3 = F(55);

  char* wp = (char*)d_ws;
  auto alloc = [&](size_t bytes) {
    char* p = wp;
    wp += (bytes + 255) & ~(size_t)255;
    return (void*)p;
  };
  ushort* memb = (ushort*)alloc((size_t)BNN * DD * 2);
  ushort* Kb   = (ushort*)alloc((size_t)BNN * DD * 2);
  ushort* Vt   = (ushort*)alloc((size_t)64 * 32 * 4096 * 2);
  ushort* wkvT = (ushort*)alloc((size_t)12 * DD * DD * 2);
  ushort* w1T  = (ushort*)alloc((size_t)6 * FFD * DD * 2);
  ushort* w2T  = (ushort*)alloc((size_t)6 * DD * FFD * 2);
  ushort* xb   = (ushort*)alloc((size_t)MMP * DD * 2);
  ushort* hb   = (ushort*)alloc((size_t)MMP * FFD * 2);
  float* x    = (float*)alloc((size_t)MMP * DD * 4);
  float* tA   = (float*)alloc((size_t)MMP * DD * 4);
  float* tB   = (float*)alloc((size_t)MMP * DD * 4);
  float* tC   = (float*)alloc((size_t)MMP * DD * 4);
  float* tD   = (float*)alloc((size_t)MMP * DD * 4);
  float* txt  = (float*)alloc((size_t)BB * NTXT * DD * 4);
  float* tK   = (float*)alloc((size_t)BB * NTXT * DD * 4);
  float* tV   = (float*)alloc((size_t)BB * NTXT * DD * 4);
  float* pacc = (float*)alloc((size_t)KC * 64 * TT * HDIM * 4);
  float* pl   = (float*)alloc((size_t)KC * 64 * TT * 4);
  float* posq = (float*)alloc((size_t)4096 * 4);
  float4* pm4 = (float4*)alloc((size_t)BNN * 16);
  float* pres = (float*)alloc((size_t)BB * DD * 4);
  float* ph1  = (float*)alloc((size_t)BB * DD * 4);
  float* ph2  = (float*)alloc((size_t)BB * DD * 4);

  // ---- one-time precomputation
  k_mem<<<BNN / 4, 256, 0, stream>>>(img, pm, wpeW, wpeb, memb);
  k_pm4<<<BNN / 256, 256, 0, stream>>>(pm, pm4);
  for (int i = 0; i < NLAY; ++i) {
    k_t2b<<<dim3(4, 4), 256, 0, stream>>>(caWk + (size_t)i * DD * DD, wkvT + (size_t)i * DD * DD, DD, DD);
    k_t2b<<<dim3(4, 4), 256, 0, stream>>>(caWv + (size_t)i * DD * DD, wkvT + (size_t)(6 + i) * DD * DD, DD, DD);
    k_t2b<<<dim3(4, 32), 256, 0, stream>>>(fW1 + (size_t)i * DD * FFD, w1T + (size_t)i * FFD * DD, DD, FFD);
    k_t2b<<<dim3(32, 4), 256, 0, stream>>>(fW2 + (size_t)i * FFD * DD, w2T + (size_t)i * DD * FFD, FFD, DD);
  }

  // ---- phase 0: text projections, x init, text cross-attn block
  k_linear256<<<32, 256, 0, stream>>>(txtf, tpW, tpb, txt, BB * NTXT, 0);
  k_linear256<<<32, 256, 0, stream>>>(txt, tWk, tbk, tK, BB * NTXT, 0);
  k_linear256<<<32, 256, 0, stream>>>(txt, tWv, tbv, tV, BB * NTXT, 0);
  k_init_x<<<MM, 256, 0, stream>>>(qe, ptok, x);
  k_linear256<<<101, 256, 0, stream>>>(x, tWq, tbq, tA, MM, 0);
  k_attn_small<<<64, 128, 0, stream>>>(tA, tK, tV, tB, NTXT);
  k_linear256<<<101, 256, 0, stream>>>(tB, tWo, tbo, tC, MM, 0);
  k_add_ln<<<MM, 256, 0, stream>>>(x, tC, tlng, tlnb, x);

  for (int i = 0; i < NLAY; ++i) {
    size_t wo = (size_t)i * DD * DD;
    // self-attention
    k_linear256<<<101, 256, 0, stream>>>(x, saWq + wo, sabq + i * DD, tA, MM, 0);
    k_linear256<<<101, 256, 0, stream>>>(x, saWk + wo, sabk + i * DD, tB, MM, 0);
    k_linear256<<<101, 256, 0, stream>>>(x, saWv + wo, sabv + i * DD, tC, MM, 0);
    k_attn_small<<<64, 128, 0, stream>>>(tA, tB, tC, tD, TT);
    k_linear256<<<101, 256, 0, stream>>>(tD, saWo + wo, sabo + i * DD, tA, MM, 0);
    k_add_ln<<<MM, 256, 0, stream>>>(x, tA, ln1g + i * DD, ln1b + i * DD, x);
    // positional query + cross-attention (MFMA)
    k_posq<<<MM, 128, 0, stream>>>(x, posW + (size_t)i * DD * 3, posb + i * 3, posq);
    k_linear256<<<101, 256, 0, stream>>>(x, caWq + wo, cabq + i * DD, tA, MM, 0);
    k_gemm_bf<1><<<dim3(256, 4), 256, 0, stream>>>(memb, wkvT + wo, cabk + i * DD, Kb, BNN, DD, DD);
    k_gemm_bf<3><<<dim3(256, 4), 256, 0, stream>>>(memb, wkvT + (size_t)(6 + i) * DD * DD, cabv + i * DD, Vt, BNN, DD, DD);
    k_cross_mfma<<<dim3(64, KC), 256, 0, stream>>>(tA, Kb, Vt, posq, pm4, beta + i * NH, pacc, pl);
    k_cross_merge<<<dim3(64, 13), 256, 0, stream>>>(pacc, pl, tB);
    k_linear256<<<101, 256, 0, stream>>>(tB, caWo + wo, cabo + i * DD, tC, MM, 0);
    k_add_ln<<<MM, 256, 0, stream>>>(x, tC, ln2g + i * DD, ln2b + i * DD, x);
    // FFN (MFMA bf16)
    k_f2b<<<(MM * DD) / 1024, 256, 0, stream>>>(x, xb, MM * DD);
    k_gemm_bf<2><<<dim3(7, 32), 256, 0, stream>>>(xb, w1T + (size_t)i * FFD * DD, fb1 + i * FFD, hb, MM, FFD, DD);
    k_gemm_bf<0><<<dim3(7, 4), 256, 0, stream>>>(hb, w2T + (size_t)i * DD * FFD, fb2 + i * DD, tA, MM, DD, FFD);
    k_add_ln<<<MM, 256, 0, stream>>>(x, tA, ln3g + i * DD, ln3b + i * DD, x);
  }

  // ---- epilogue
  k_add_ln<<<MM, 256, 0, stream>>>(x, nullptr, fing, finb, x);
  k_copy_hs<<<BB * NQRY, 256, 0, stream>>>(x, (float*)d_out);
  k_gather_pres<<<BB, 256, 0, stream>>>(x, pres);
  k_linear256<<<1, 256, 0, stream>>>(pres, pW1, pb1, ph1, BB, 1);
  k_linear256<<<1, 256, 0, stream>>>(ph1, pW2, pb2, ph2, BB, 1);
  k_logit<<<1, 256, 0, stream>>>(ph2, pW3, pb3, (float*)d_out + (size_t)BB * NQRY * DD);
}

// Round 3
// 1303.216 us; speedup vs baseline: 9.6302x; 1.4052x over previous
//
#include <hip/hip_runtime.h>
#include <math.h>

#define DD 256
#define NH 8
#define HDIM 32
#define NLAY 6
#define NQRY 100
#define TT 101
#define BB 8
#define NN 4096
#define NTXT 32
#define FFD 2048
#define MM (BB*TT)      // 808 = 101*8
#define MMP 896         // 7*128 padded rows
#define BNN (BB*NN)     // 32768
#define KC 8
#define KPC (NN/KC)     // 512

typedef __bf16 bf16x8 __attribute__((ext_vector_type(8)));
typedef float f32x4v __attribute__((ext_vector_type(4)));
typedef unsigned int u32x4 __attribute__((ext_vector_type(4)));
typedef unsigned int u32x2 __attribute__((ext_vector_type(2)));

__device__ __forceinline__ ushort f2b(float f) {
  unsigned u = __builtin_bit_cast(unsigned, f);
  u += 0x7FFF + ((u >> 16) & 1);
  return (ushort)(u >> 16);
}
__device__ __forceinline__ unsigned pk2(float lo, float hi) {
  return (unsigned)f2b(lo) | ((unsigned)f2b(hi) << 16);
}
__device__ __forceinline__ f32x4v mfma16(bf16x8 a, bf16x8 b, f32x4v c) {
  return __builtin_amdgcn_mfma_f32_16x16x32_bf16(a, b, c, 0, 0, 0);
}

// ---------------- shared MFMA GEMM core: 128x64 tile, BK=64, swizzled LDS ----------------
__device__ __forceinline__ void gemm_core(const ushort* __restrict__ A, size_t lda,
                                          const ushort* __restrict__ Bt, size_t ldb,
                                          int m0, int n0, int kBeg, int kEnd,
                                          char* AsB, char* BsB, int t,
                                          f32x4v acc[2][4]) {
  int w = t >> 6, l = t & 63, lq = l & 15, lg = l >> 4;
  int acol = (t & 7) * 8;
  for (int k0 = kBeg; k0 < kEnd; k0 += 64) {
    __syncthreads();
#pragma unroll
    for (int p = 0; p < 4; ++p) {
      int row = (t >> 3) + p * 32;
      u32x4 v = *(const u32x4*)(A + (size_t)(m0 + row) * lda + k0 + acol);
      *(u32x4*)(AsB + row * 128 + ((acol * 2) ^ ((row & 7) << 4))) = v;
    }
#pragma unroll
    for (int p = 0; p < 2; ++p) {
      int row = (t >> 3) + p * 32;
      u32x4 v = *(const u32x4*)(Bt + (size_t)(n0 + row) * ldb + k0 + acol);
      *(u32x4*)(BsB + row * 128 + ((acol * 2) ^ ((row & 7) << 4))) = v;
    }
    __syncthreads();
#pragma unroll
    for (int ks = 0; ks < 2; ++ks) {
      bf16x8 af[2], bfr[4];
#pragma unroll
      for (int mt = 0; mt < 2; ++mt) {
        int row = w * 32 + mt * 16 + lq;
        int kb = ks * 64 + lg * 16;
        af[mt] = __builtin_bit_cast(
            bf16x8, *(const u32x4*)(AsB + row * 128 + (kb ^ ((row & 7) << 4))));
      }
#pragma unroll
      for (int nt = 0; nt < 4; ++nt) {
        int row = nt * 16 + lq;
        int kb = ks * 64 + lg * 16;
        bfr[nt] = __builtin_bit_cast(
            bf16x8, *(const u32x4*)(BsB + row * 128 + (kb ^ ((row & 7) << 4))));
      }
#pragma unroll
      for (int mt = 0; mt < 2; ++mt)
#pragma unroll
        for (int nt = 0; nt < 4; ++nt) acc[mt][nt] = mfma16(af[mt], bfr[nt], acc[mt][nt]);
    }
  }
}

// ---------------------------------------------------------------- enc bf16 [BNN][64]
__global__ __launch_bounds__(256) void k_enc(const float* __restrict__ pm,
                                             ushort* __restrict__ encb) {
  int t = threadIdx.x;
  int row = blockIdx.x * 32 + (t >> 3);
  int kb = (t & 7) * 8;
  ushort o[8];
#pragma unroll
  for (int u = 0; u < 8; ++u) {
    int k = kb + u;
    float val = 0.f;
    if (k < 60) {
      int c = k / 20, jj = k % 20;
      float f = (float)(1 << (jj % 10));
      float a = pm[(size_t)row * 3 + c] * f;
      val = (jj < 10) ? sinf(a) : cosf(a);
    }
    o[u] = f2b(val);
  }
  *(u32x4*)(encb + (size_t)row * 64 + kb) = *(const u32x4*)o;
}

// -------------------------------------------------- wpeT bf16 [256][64] (pad K 60->64)
__global__ __launch_bounds__(256) void k_wpet(const float* __restrict__ wpeW,
                                              ushort* __restrict__ wpeT) {
  int n = blockIdx.x * 16 + (threadIdx.x >> 4);
  int k = (threadIdx.x & 15) * 4;
  ushort o[4];
#pragma unroll
  for (int u = 0; u < 4; ++u) {
    int kk = k + u;
    o[u] = (kk < 60) ? f2b(wpeW[(size_t)kk * DD + n]) : (ushort)0;
  }
  *(u32x2*)(wpeT + (size_t)n * 64 + k) = *(const u32x2*)o;
}

// -------------------------- memb = bf16(enc@wpeW + wpeb + img) via MFMA, grid (256,4)
__global__ __launch_bounds__(256) void k_gemm_mem(const ushort* __restrict__ encb,
                                                  const ushort* __restrict__ wpeT,
                                                  const float* __restrict__ wpeb,
                                                  const float* __restrict__ img,
                                                  ushort* __restrict__ memb) {
  __shared__ __align__(16) char AsB[16384];
  __shared__ __align__(16) char BsB[8192];
  int m0 = blockIdx.x * 128, n0 = blockIdx.y * 64;
  f32x4v acc[2][4] = {};
  gemm_core(encb, 64, wpeT, 64, m0, n0, 0, 64, AsB, BsB, threadIdx.x, acc);
  int t = threadIdx.x, w = t >> 6, l = t & 63, lq = l & 15, lg = l >> 4;
#pragma unroll
  for (int nt = 0; nt < 4; ++nt) {
    int n = n0 + nt * 16 + lq;
    float bv = wpeb[n];
#pragma unroll
    for (int mt = 0; mt < 2; ++mt) {
      int rowg = m0 + w * 32 + mt * 16 + lg * 4;
      f32x4v a = acc[mt][nt];
#pragma unroll
      for (int r = 0; r < 4; ++r)
        memb[(size_t)(rowg + r) * DD + n] = f2b(a[r] + bv + img[(size_t)(rowg + r) * DD + n]);
    }
  }
}

// ------------------------------- all weight transposes f32->bf16^T in ONE dispatch
__global__ __launch_bounds__(256) void k_t2b_all(const float* __restrict__ caWk,
                                                 const float* __restrict__ caWv,
                                                 const float* __restrict__ fW1,
                                                 const float* __restrict__ fW2,
                                                 ushort* __restrict__ wkvT,
                                                 ushort* __restrict__ w1T,
                                                 ushort* __restrict__ w2T) {
  __shared__ ushort T[64][72];
  int id = blockIdx.x;
  const float* src;
  ushort* dst;
  int K, N, k0, n0;
  if (id < 192) {
    int mi = id >> 4, ti = id & 15;
    src = (mi < 6) ? caWk + (size_t)mi * DD * DD : caWv + (size_t)(mi - 6) * DD * DD;
    dst = wkvT + (size_t)mi * DD * DD;
    K = DD; N = DD; k0 = (ti >> 2) * 64; n0 = (ti & 3) * 64;
  } else if (id < 960) {
    int t2 = id - 192, mi = t2 >> 7, ti = t2 & 127;
    src = fW1 + (size_t)mi * DD * FFD;
    dst = w1T + (size_t)mi * DD * FFD;
    K = DD; N = FFD; k0 = (ti >> 5) * 64; n0 = (ti & 31) * 64;
  } else {
    int t2 = id - 960, mi = t2 >> 7, ti = t2 & 127;
    src = fW2 + (size_t)mi * DD * FFD;
    dst = w2T + (size_t)mi * DD * FFD;
    K = FFD; N = DD; k0 = (ti >> 2) * 64; n0 = (ti & 3) * 64;
  }
  int t = threadIdx.x;
  int kk = t >> 4, nn4 = (t & 15) * 4;
#pragma unroll
  for (int p = 0; p < 4; ++p) {
    int krow = kk + p * 16;
    float4 v = *(const float4*)(src + (size_t)(k0 + krow) * N + n0 + nn4);
    T[nn4 + 0][krow] = f2b(v.x);
    T[nn4 + 1][krow] = f2b(v.y);
    T[nn4 + 2][krow] = f2b(v.z);
    T[nn4 + 3][krow] = f2b(v.w);
  }
  __syncthreads();
  int nn = t >> 3, kk8 = (t & 7) * 8;
#pragma unroll
  for (int p = 0; p < 2; ++p) {
    int nrow = nn + p * 32;
    u32x4 v = *(const u32x4*)(&T[nrow][kk8]);
    *(u32x4*)(dst + (size_t)(n0 + nrow) * K + k0 + kk8) = v;
  }
}

// ------------------------------------------------------------ pm4 = (x, y, z, |p|^2)
__global__ __launch_bounds__(256) void k_pm4(const float* __restrict__ pm,
                                             float4* __restrict__ pm4) {
  int i = blockIdx.x * 256 + threadIdx.x;
  float x = pm[(size_t)i * 3 + 0];
  float y = pm[(size_t)i * 3 + 1];
  float z = pm[(size_t)i * 3 + 2];
  float4 v;
  v.x = x; v.y = y; v.z = z; v.w = x * x + y * y + z * z;
  pm4[i] = v;
}

// ------------------------------------------------- y = act(x @ W + b), K=N=256 (f32)
__global__ __launch_bounds__(256) void k_linear256(const float* __restrict__ x,
                                                   const float* __restrict__ W,
                                                   const float* __restrict__ b,
                                                   float* __restrict__ y,
                                                   int Mr, int relu) {
  int r0 = blockIdx.x * 8;
  int d = threadIdx.x;
  __shared__ float xs[8][DD];
  for (int i = threadIdx.x; i < 8 * DD; i += 256) {
    int r = i >> 8, k = i & 255;
    xs[r][k] = (r0 + r < Mr) ? x[(size_t)(r0 + r) * DD + k] : 0.f;
  }
  __syncthreads();
  float acc[8] = {};
  for (int k = 0; k < DD; ++k) {
    float w = W[k * DD + d];
#pragma unroll
    for (int r = 0; r < 8; ++r) acc[r] += xs[r][k] * w;
  }
  float bb = b[d];
#pragma unroll
  for (int r = 0; r < 8; ++r) {
    if (r0 + r < Mr) {
      float v = acc[r] + bb;
      if (relu) v = fmaxf(v, 0.f);
      y[(size_t)(r0 + r) * DD + d] = v;
    }
  }
}

// --------------------------- up-to-3 projections in one dispatch, grid (rows/8, nmat)
struct XPA {
  const float* W0; const float* B0; float* O0;
  const float* W1; const float* B1; float* O1;
  const float* W2; const float* B2; float* O2;
};
__global__ __launch_bounds__(256) void k_xproj(const float* __restrict__ in, XPA a) {
  const float* W; const float* bp; float* o;
  if (blockIdx.y == 0) { W = a.W0; bp = a.B0; o = a.O0; }
  else if (blockIdx.y == 1) { W = a.W1; bp = a.B1; o = a.O1; }
  else { W = a.W2; bp = a.B2; o = a.O2; }
  int r0 = blockIdx.x * 8, d = threadIdx.x;
  __shared__ float xs[8][DD];
  for (int i = threadIdx.x; i < 8 * DD; i += 256) {
    int r = i >> 8, k = i & 255;
    xs[r][k] = in[(size_t)(r0 + r) * DD + k];
  }
  __syncthreads();
  float acc[8] = {};
  for (int k = 0; k < DD; ++k) {
    float w = W[k * DD + d];
#pragma unroll
    for (int r = 0; r < 8; ++r) acc[r] += xs[r][k] * w;
  }
  float bb = bp[d];
#pragma unroll
  for (int r = 0; r < 8; ++r) o[(size_t)(r0 + r) * DD + d] = acc[r] + bb;
}

// ------------- fused: y = LN(xres + in@Wo + bo); optionally +q-proj +posq, +bf16 copy
template <int QPROJ, int XB>
__global__ __launch_bounds__(256) void k_o_ln(
    const float* __restrict__ in, const float* __restrict__ Wo,
    const float* __restrict__ bo, const float* __restrict__ xres,
    const float* __restrict__ g, const float* __restrict__ be,
    float* __restrict__ xout, ushort* __restrict__ xbout,
    const float* __restrict__ Wq, const float* __restrict__ bq,
    float* __restrict__ qout, const float* __restrict__ Wp,
    const float* __restrict__ bp, float* __restrict__ pqout) {
  int r0 = blockIdx.x * 8, d = threadIdx.x;
  int lane = d & 63, wid = d >> 6;
  __shared__ float xs[8][DD];
  __shared__ float rS[8][4], rS2[8][4];
  __shared__ float rP[8][3][4];
  for (int i = threadIdx.x; i < 8 * DD; i += 256) {
    int r = i >> 8, k = i & 255;
    xs[r][k] = in[(size_t)(r0 + r) * DD + k];
  }
  __syncthreads();
  float acc[8] = {};
  for (int k = 0; k < DD; ++k) {
    float w = Wo[k * DD + d];
#pragma unroll
    for (int r = 0; r < 8; ++r) acc[r] += xs[r][k] * w;
  }
  float bb = bo[d];
  float v[8];
#pragma unroll
  for (int r = 0; r < 8; ++r) v[r] = acc[r] + bb + xres[(size_t)(r0 + r) * DD + d];
#pragma unroll
  for (int r = 0; r < 8; ++r) {
    float s = v[r], s2 = v[r] * v[r];
#pragma unroll
    for (int o = 1; o < 64; o <<= 1) {
      s += __shfl_xor(s, o, 64);
      s2 += __shfl_xor(s2, o, 64);
    }
    if (lane == 0) { rS[r][wid] = s; rS2[r][wid] = s2; }
  }
  __syncthreads();
  float ln[8];
  float gd = g[d], bd = be[d];
#pragma unroll
  for (int r = 0; r < 8; ++r) {
    float s = rS[r][0] + rS[r][1] + rS[r][2] + rS[r][3];
    float s2 = rS2[r][0] + rS2[r][1] + rS2[r][2] + rS2[r][3];
    float m = s * (1.f / DD);
    float var = s2 * (1.f / DD) - m * m;
    float inv = rsqrtf(var + 1e-5f);
    ln[r] = (v[r] - m) * inv * gd + bd;
    xout[(size_t)(r0 + r) * DD + d] = ln[r];
    if (XB) xbout[(size_t)(r0 + r) * DD + d] = f2b(ln[r]);
  }
  if (QPROJ) {
    // posq partials (before overwriting xs is fine; rP independent)
    float pw0 = Wp[d * 3 + 0], pw1 = Wp[d * 3 + 1], pw2 = Wp[d * 3 + 2];
#pragma unroll
    for (int r = 0; r < 8; ++r) {
#pragma unroll
      for (int c = 0; c < 3; ++c) {
        float s = ln[r] * (c == 0 ? pw0 : (c == 1 ? pw1 : pw2));
#pragma unroll
        for (int o = 1; o < 64; o <<= 1) s += __shfl_xor(s, o, 64);
        if (lane == 0) rP[r][c][wid] = s;
      }
    }
    // q-projection on LN'd rows (xs overwrite safe: all threads past first sync)
#pragma unroll
    for (int r = 0; r < 8; ++r) xs[r][d] = ln[r];
    __syncthreads();
    float acc2[8] = {};
    for (int k = 0; k < DD; ++k) {
      float w = Wq[k * DD + d];
#pragma unroll
      for (int r = 0; r < 8; ++r) acc2[r] += xs[r][k] * w;
    }
    float bq_ = bq[d];
#pragma unroll
    for (int r = 0; r < 8; ++r) qout[(size_t)(r0 + r) * DD + d] = acc2[r] + bq_;
    if (d < 24) {
      int r = d / 3, c = d % 3;
      float s = rP[r][c][0] + rP[r][c][1] + rP[r][c][2] + rP[r][c][3];
      pqout[(size_t)(r0 + r) * 3 + c] = s + bp[c];
    }
  }
}

// --------------------------------------------------------------------------- x init
__global__ __launch_bounds__(256) void k_init_x(const float* __restrict__ qe,
                                                const float* __restrict__ pt,
                                                float* __restrict__ x) {
  int r = blockIdx.x, d = threadIdx.x;
  int t = r % TT;
  x[(size_t)r * DD + d] = (t < NQRY) ? qe[t * DD + d] : pt[d];
}

// ------------------------- small attention (no bias), f32, fixed-base softmax
__global__ __launch_bounds__(128) void k_attn_small(const float* __restrict__ q,
                                                    const float* __restrict__ k,
                                                    const float* __restrict__ v,
                                                    float* __restrict__ out,
                                                    int NK) {
  int bh = blockIdx.x;
  int b = bh >> 3, h = bh & 7;
  __shared__ float Ks[TT][HDIM];
  __shared__ float Vs[TT][HDIM];
  for (int i = threadIdx.x; i < NK * HDIM; i += 128) {
    int n = i >> 5, j = i & 31;
    Ks[n][j] = k[(size_t)(b * NK + n) * DD + h * HDIM + j];
    Vs[n][j] = v[(size_t)(b * NK + n) * DD + h * HDIM + j];
  }
  __syncthreads();
  int t = threadIdx.x;
  if (t >= TT) return;
  float qv[HDIM];
  const float* qp = q + (size_t)(b * TT + t) * DD + h * HDIM;
#pragma unroll
  for (int j = 0; j < HDIM; ++j) qv[j] = qp[j];
  const float sc = 0.17677669529663687f * 1.4426950408889634f;
  float l = 0.f, acc[HDIM] = {};
  for (int n = 0; n < NK; ++n) {
    float s = 0.f;
#pragma unroll
    for (int j = 0; j < HDIM; ++j) s += qv[j] * Ks[n][j];
    float p = exp2f(s * sc);
    l += p;
#pragma unroll
    for (int j = 0; j < HDIM; ++j) acc[j] += p * Vs[n][j];
  }
  float inv = 1.f / l;
  float* op = out + (size_t)(b * TT + t) * DD + h * HDIM;
#pragma unroll
  for (int j = 0; j < HDIM; ++j) op[j] = acc[j] * inv;
}

// ------------- fused K+V projection of memb: grid (256, 8): y<4 -> K, y>=4 -> V^T
__global__ __launch_bounds__(256) void k_gemm_kv(const ushort* __restrict__ A,
                                                 const ushort* __restrict__ Btk,
                                                 const ushort* __restrict__ Btv,
                                                 const float* __restrict__ bk,
                                                 const float* __restrict__ bv,
                                                 ushort* __restrict__ Kb,
                                                 ushort* __restrict__ Vt) {
  __shared__ __align__(16) char AsB[16384];
  __shared__ __align__(16) char BsB[8192];
  int isV = blockIdx.y >= 4;
  int n0 = (isV ? blockIdx.y - 4 : blockIdx.y) * 64;
  int m0 = blockIdx.x * 128;
  const ushort* Bt = isV ? Btv : Btk;
  f32x4v acc[2][4] = {};
  gemm_core(A, 256, Bt, 256, m0, n0, 0, 256, AsB, BsB, threadIdx.x, acc);
  int t = threadIdx.x, w = t >> 6, l = t & 63, lq = l & 15, lg = l >> 4;
  const float* bias = isV ? bv : bk;
#pragma unroll
  for (int nt = 0; nt < 4; ++nt) {
    int n = n0 + nt * 16 + lq;
    float bvv = bias[n];
#pragma unroll
    for (int mt = 0; mt < 2; ++mt) {
      int rowg = m0 + w * 32 + mt * 16 + lg * 4;
      f32x4v a = acc[mt][nt];
      a[0] += bvv; a[1] += bvv; a[2] += bvv; a[3] += bvv;
      if (!isV) {
#pragma unroll
        for (int r = 0; r < 4; ++r) Kb[(size_t)(rowg + r) * DD + n] = f2b(a[r]);
      } else {
        int b = rowg >> 12, key = rowg & 4095;
        int h = n >> 5, dd = n & 31;
        u32x2 pv;
        pv[0] = pk2(a[0], a[1]);
        pv[1] = pk2(a[2], a[3]);
        *(u32x2*)(Vt + ((size_t)((b * 8 + h) * 32 + dd) * 4096 + key)) = pv;
      }
    }
  }
}

// ------------------------------------------- FFN1: hb = bf16(relu(xb@W1^T + b1))
__global__ __launch_bounds__(256) void k_ffn1(const ushort* __restrict__ A,
                                              const ushort* __restrict__ Bt,
                                              const float* __restrict__ bias,
                                              ushort* __restrict__ C) {
  __shared__ __align__(16) char AsB[16384];
  __shared__ __align__(16) char BsB[8192];
  int m0 = blockIdx.x * 128, n0 = blockIdx.y * 64;
  f32x4v acc[2][4] = {};
  gemm_core(A, 256, Bt, 256, m0, n0, 0, 256, AsB, BsB, threadIdx.x, acc);
  int t = threadIdx.x, w = t >> 6, l = t & 63, lq = l & 15, lg = l >> 4;
#pragma unroll
  for (int nt = 0; nt < 4; ++nt) {
    int n = n0 + nt * 16 + lq;
    float bv = bias[n];
#pragma unroll
    for (int mt = 0; mt < 2; ++mt) {
      int rowg = m0 + w * 32 + mt * 16 + lg * 4;
      f32x4v a = acc[mt][nt];
#pragma unroll
      for (int r = 0; r < 4; ++r)
        C[(size_t)(rowg + r) * FFD + n] = f2b(fmaxf(a[r] + bv, 0.f));
    }
  }
}

// ----------------------- FFN2 split-K: partials P[z][row][col], grid (7, 4, 8)
__global__ __launch_bounds__(256) void k_ffn2sk(const ushort* __restrict__ A,
                                                const ushort* __restrict__ Bt,
                                                float* __restrict__ P) {
  __shared__ __align__(16) char AsB[16384];
  __shared__ __align__(16) char BsB[8192];
  int m0 = blockIdx.x * 128, n0 = blockIdx.y * 64, z = blockIdx.z;
  f32x4v acc[2][4] = {};
  gemm_core(A, FFD, Bt, FFD, m0, n0, z * 256, z * 256 + 256, AsB, BsB, threadIdx.x, acc);
  int t = threadIdx.x, w = t >> 6, l = t & 63, lq = l & 15, lg = l >> 4;
#pragma unroll
  for (int nt = 0; nt < 4; ++nt) {
    int n = n0 + nt * 16 + lq;
#pragma unroll
    for (int mt = 0; mt < 2; ++mt) {
      int rowg = m0 + w * 32 + mt * 16 + lg * 4;
      f32x4v a = acc[mt][nt];
#pragma unroll
      for (int r = 0; r < 4; ++r)
        P[((size_t)z * MMP + rowg + r) * DD + n] = a[r];
    }
  }
}

// -------------------- FFN2 reduce + bias + residual + LN3 -> x (one row per block)
__global__ __launch_bounds__(256) void k_red_ln3(const float* __restrict__ P,
                                                 const float* __restrict__ bias,
                                                 const float* __restrict__ xres,
                                                 const float* __restrict__ g,
                                                 const float* __restrict__ be,
                                                 float* __restrict__ xout) {
  int row = blockIdx.x, d = threadIdx.x;
  float a = xres[(size_t)row * DD + d] + bias[d];
#pragma unroll
  for (int z = 0; z < 8; ++z) a += P[((size_t)z * MMP + row) * DD + d];
  float s = a, s2 = a * a;
#pragma unroll
  for (int o = 1; o < 64; o <<= 1) {
    s += __shfl_xor(s, o, 64);
    s2 += __shfl_xor(s2, o, 64);
  }
  __shared__ float ws[4], ws2[4];
  int wid = d >> 6;
  if ((d & 63) == 0) { ws[wid] = s; ws2[wid] = s2; }
  __syncthreads();
  s = ws[0] + ws[1] + ws[2] + ws[3];
  s2 = ws2[0] + ws2[1] + ws2[2] + ws2[3];
  float m = s * (1.f / DD);
  float var = s2 * (1.f / DD) - m * m;
  float inv = rsqrtf(var + 1e-5f);
  xout[(size_t)row * DD + d] = (a - m) * inv * g[d] + be[d];
}

// ------------------- MFMA flash cross-attention with distance bias (as R2, passed)
__global__ __launch_bounds__(256) void k_cross_mfma(
    const float* __restrict__ Q, const ushort* __restrict__ Kb,
    const ushort* __restrict__ Vt, const float* __restrict__ posq,
    const float4* __restrict__ pm4, const float* __restrict__ betaL,
    float* __restrict__ pacc, float* __restrict__ pl) {
  int bh = blockIdx.x, kc = blockIdx.y;
  int b = bh >> 3, h = bh & 7;
  int t = threadIdx.x, w = t >> 6, l = t & 63, lq = l & 15, lg = l >> 4;
  const float L2E = 1.4426950408889634f;
  const float c1 = 0.17677669529663687f * L2E;
  float spb = log1pf(expf(betaL[h]));
  float cb = spb * L2E;

  __shared__ float4 pm4s[KPC];
  __shared__ ushort Plds[4][2][16][40];

  int kbase = b * NN + kc * KPC;
  for (int i = t; i < KPC; i += 256) pm4s[i] = pm4[kbase + i];
  __syncthreads();

  const f32x4v Z = {0.f, 0.f, 0.f, 0.f};
  bf16x8 qfb[2];
  float a0[2], px[2], py[2], pz[2];
  f32x4v oacc[2][2] = {};
  float lsum[2] = {0.f, 0.f};

#pragma unroll
  for (int qi = 0; qi < 2; ++qi) {
    int qt = w * 2 + qi;
    int qidx = qt * 16 + lq;
    int qc = qidx < TT ? qidx : TT - 1;
    size_t xr = (size_t)(b * TT + qc);
    const float* qp = Q + xr * 256 + h * 32 + lg * 8;
    float4 q0 = *(const float4*)qp;
    float4 q1 = *(const float4*)(qp + 4);
    u32x4 qv;
    qv[0] = pk2(q0.x * c1, q0.y * c1);
    qv[1] = pk2(q0.z * c1, q0.w * c1);
    qv[2] = pk2(q1.x * c1, q1.y * c1);
    qv[3] = pk2(q1.z * c1, q1.w * c1);
    qfb[qi] = __builtin_bit_cast(bf16x8, qv);
    float qx = posq[xr * 3 + 0], qy = posq[xr * 3 + 1], qz = posq[xr * 3 + 2];
    a0[qi] = -cb * (qx * qx + qy * qy + qz * qz);
    px[qi] = 2.f * cb * qx;
    py[qi] = 2.f * cb * qy;
    pz[qi] = 2.f * cb * qz;
  }

  for (int kk = 0; kk < KPC; kk += 32) {
    bf16x8 kf[2], vf[2];
#pragma unroll
    for (int t2 = 0; t2 < 2; ++t2)
      kf[t2] = __builtin_bit_cast(
          bf16x8, *(const u32x4*)(Kb + (size_t)(kbase + kk + t2 * 16 + lq) * 256 +
                                  h * 32 + lg * 8));
#pragma unroll
    for (int dt = 0; dt < 2; ++dt)
      vf[dt] = __builtin_bit_cast(
          bf16x8, *(const u32x4*)(Vt + (size_t)(bh * 32 + dt * 16 + lq) * 4096 +
                                  kc * KPC + kk + lg * 8));
    float bx[2][4], by[2][4], bz[2][4], b0[2][4];
#pragma unroll
    for (int t2 = 0; t2 < 2; ++t2)
#pragma unroll
      for (int r = 0; r < 4; ++r) {
        float4 pv = pm4s[kk + t2 * 16 + lg * 4 + r];
        bx[t2][r] = pv.x; by[t2][r] = pv.y; bz[t2][r] = pv.z;
        b0[t2][r] = cb * pv.w;
      }
#pragma unroll
    for (int qi = 0; qi < 2; ++qi) {
      f32x4v s0 = mfma16(kf[0], qfb[qi], Z);
      f32x4v s1 = mfma16(kf[1], qfb[qi], Z);
      float p[2][4];
#pragma unroll
      for (int t2 = 0; t2 < 2; ++t2) {
#pragma unroll
        for (int r = 0; r < 4; ++r) {
          float sv = (t2 == 0) ? s0[r] : s1[r];
          float bias = fmaf(px[qi], bx[t2][r],
                       fmaf(py[qi], by[t2][r],
                       fmaf(pz[qi], bz[t2][r], a0[qi] - b0[t2][r])));
          p[t2][r] = exp2f(sv + bias);
        }
        lsum[qi] += (p[t2][0] + p[t2][1]) + (p[t2][2] + p[t2][3]);
      }
      u32x2 w0, w1;
      w0[0] = pk2(p[0][0], p[0][1]);
      w0[1] = pk2(p[0][2], p[0][3]);
      w1[0] = pk2(p[1][0], p[1][1]);
      w1[1] = pk2(p[1][2], p[1][3]);
      *(u32x2*)(&Plds[w][qi][lq][lg * 4]) = w0;
      *(u32x2*)(&Plds[w][qi][lq][16 + lg * 4]) = w1;
      bf16x8 pf = __builtin_bit_cast(bf16x8, *(const u32x4*)(&Plds[w][qi][lq][lg * 8]));
      oacc[qi][0] = mfma16(vf[0], pf, oacc[qi][0]);
      oacc[qi][1] = mfma16(vf[1], pf, oacc[qi][1]);
    }
  }

#pragma unroll
  for (int qi = 0; qi < 2; ++qi) {
    float lv = lsum[qi];
    lv += __shfl_xor(lv, 16, 64);
    lv += __shfl_xor(lv, 32, 64);
    int qt = w * 2 + qi;
    int qidx = qt * 16 + lq;
    if (qidx < TT) {
      size_t o = ((size_t)(kc * 64 + bh) * TT + qidx) * 32;
#pragma unroll
      for (int dt = 0; dt < 2; ++dt) {
        f32x4v a = oacc[qi][dt];
        float4 st;
        st.x = a[0]; st.y = a[1]; st.z = a[2]; st.w = a[3];
        *(float4*)(pacc + o + dt * 16 + lg * 4) = st;
      }
      if (lg == 0) pl[(size_t)(kc * 64 + bh) * TT + qidx] = lv;
    }
  }
}

__global__ __launch_bounds__(256) void k_cross_merge(const float* __restrict__ pacc,
                                                     const float* __restrict__ pl,
                                                     float* __restrict__ out) {
  int bh = blockIdx.x;
  int b = bh >> 3, h = bh & 7;
  int q8 = blockIdx.y * 8 + (threadIdx.x >> 5);
  int j = threadIdx.x & 31;
  if (q8 >= TT) return;
  float sa = 0.f, sl = 0.f;
  for (int kc = 0; kc < KC; ++kc) {
    sa += pacc[(((size_t)kc * 64 + bh) * TT + q8) * HDIM + j];
    sl += pl[((size_t)kc * 64 + bh) * TT + q8];
  }
  out[((size_t)(b * TT + q8)) * DD + h * HDIM + j] = sa / sl;
}

// ------------------------ final LN + scatter to hs / pres (one row per block)
__global__ __launch_bounds__(256) void k_fin(const float* __restrict__ x,
                                             const float* __restrict__ g,
                                             const float* __restrict__ be,
                                             float* __restrict__ hs,
                                             float* __restrict__ pres) {
  int row = blockIdx.x, d = threadIdx.x;
  int b = row / TT, tq = row % TT;
  float v = x[(size_t)row * DD + d];
  float s = v, s2 = v * v;
#pragma unroll
  for (int o = 1; o < 64; o <<= 1) {
    s += __shfl_xor(s, o, 64);
    s2 += __shfl_xor(s2, o, 64);
  }
  __shared__ float ws[4], ws2[4];
  int wid = d >> 6;
  if ((d & 63) == 0) { ws[wid] = s; ws2[wid] = s2; }
  __syncthreads();
  s = ws[0] + ws[1] + ws[2] + ws[3];
  s2 = ws2[0] + ws2[1] + ws2[2] + ws2[3];
  float m = s * (1.f / DD);
  float var = s2 * (1.f / DD) - m * m;
  float inv = rsqrtf(var + 1e-5f);
  float r = (v - m) * inv * g[d] + be[d];
  if (tq < NQRY) hs[((size_t)(b * NQRY + tq)) * DD + d] = r;
  else pres[(size_t)b * DD + d] = r;
}

__global__ __launch_bounds__(256) void k_logit(const float* __restrict__ h2,
                                               const float* __restrict__ W3,
                                               const float* __restrict__ b3,
                                               float* __restrict__ out) {
  int r = threadIdx.x >> 5, lane = threadIdx.x & 31;
  float s = 0.f;
  for (int k = lane; k < DD; k += 32) s += h2[r * DD + k] * W3[k];
#pragma unroll
  for (int o = 16; o; o >>= 1) s += __shfl_xor(s, o, 32);
  if (lane == 0) out[r] = s + b3[0];
}

// =======================================================================================
extern "C" void kernel_launch(void* const* d_in, const int* in_sizes, int n_in,
                              void* d_out, int out_size, void* d_ws, size_t ws_size,
                              hipStream_t stream) {
  (void)in_sizes; (void)n_in; (void)out_size; (void)ws_size;
  auto F = [&](int i) { return (const float*)d_in[i]; };
  const float* img   = F(0);
  const float* txtf  = F(1);
  const float* pm    = F(2);
  const float* qe    = F(3);
  const float* ptok  = F(4);
  const float* tpW   = F(5);
  const float* tpb   = F(6);
  const float* tWq   = F(7);  const float* tbq = F(8);
  const float* tWk   = F(9);  const float* tbk = F(10);
  const float* tWv   = F(11); const float* tbv = F(12);
  const float* tWo   = F(13); const float* tbo = F(14);
  const float* tlng  = F(15); const float* tlnb = F(16);
  const float* wpeW  = F(17); const float* wpeb = F(18);
  const float* saWq  = F(19); const float* sabq = F(20);
  const float* saWk  = F(21); const float* sabk = F(22);
  const float* saWv  = F(23); const float* sabv = F(24);
  const float* saWo  = F(25); const float* sabo = F(26);
  const float* caWq  = F(27); const float* cabq = F(28);
  const float* caWk  = F(29); const float* cabk = F(30);
  const float* caWv  = F(31); const float* cabv = F(32);
  const float* caWo  = F(33); const float* cabo = F(34);
  const float* fW1   = F(35); const float* fb1 = F(36);
  const float* fW2   = F(37); const float* fb2 = F(38);
  const float* ln1g  = F(39); const float* ln1b = F(40);
  const float* ln2g  = F(41); const float* ln2b = F(42);
  const float* ln3g  = F(43); const float* ln3b = F(44);
  const float* posW  = F(45); const float* posb = F(46);
  const float* beta  = F(47);
  const float* fing  = F(48); const float* finb = F(49);
  const float* pW1   = F(50); const float* pb1 = F(51);
  const float* pW2   = F(52); const float* pb2 = F(53);
  const float* pW3   = F(54); const float* pb3 = F(55);

  char* wp = (char*)d_ws;
  auto alloc = [&](size_t bytes) {
    char* p = wp;
    wp += (bytes + 255) & ~(size_t)255;
    return (void*)p;
  };
  ushort* encb = (ushort*)alloc((size_t)BNN * 64 * 2);
  ushort* wpeT = (ushort*)alloc((size_t)DD * 64 * 2);
  ushort* memb = (ushort*)alloc((size_t)BNN * DD * 2);
  ushort* Kb   = (ushort*)alloc((size_t)BNN * DD * 2);
  ushort* Vt   = (ushort*)alloc((size_t)64 * 32 * 4096 * 2);
  ushort* wkvT = (ushort*)alloc((size_t)12 * DD * DD * 2);
  ushort* w1T  = (ushort*)alloc((size_t)6 * FFD * DD * 2);
  ushort* w2T  = (ushort*)alloc((size_t)6 * DD * FFD * 2);
  ushort* xb   = (ushort*)alloc((size_t)MMP * DD * 2);
  ushort* hb   = (ushort*)alloc((size_t)MMP * FFD * 2);
  float* fp2  = (float*)alloc((size_t)8 * MMP * DD * 4);
  float* x    = (float*)alloc((size_t)MMP * DD * 4);
  float* tA   = (float*)alloc((size_t)MMP * DD * 4);
  float* tB   = (float*)alloc((size_t)MMP * DD * 4);
  float* tC   = (float*)alloc((size_t)MMP * DD * 4);
  float* tD   = (float*)alloc((size_t)MMP * DD * 4);
  float* txt  = (float*)alloc((size_t)BB * NTXT * DD * 4);
  float* tK   = (float*)alloc((size_t)BB * NTXT * DD * 4);
  float* tV   = (float*)alloc((size_t)BB * NTXT * DD * 4);
  float* pacc = (float*)alloc((size_t)KC * 64 * TT * HDIM * 4);
  float* pl   = (float*)alloc((size_t)KC * 64 * TT * 4);
  float* posq = (float*)alloc((size_t)4096 * 4);
  float4* pm4 = (float4*)alloc((size_t)BNN * 16);
  float* pres = (float*)alloc((size_t)BB * DD * 4);
  float* ph1  = (float*)alloc((size_t)BB * DD * 4);
  float* ph2  = (float*)alloc((size_t)BB * DD * 4);

  // ---- prologue
  k_enc<<<BNN / 32, 256, 0, stream>>>(pm, encb);
  k_wpet<<<16, 256, 0, stream>>>(wpeW, wpeT);
  k_pm4<<<BNN / 256, 256, 0, stream>>>(pm, pm4);
  k_t2b_all<<<1728, 256, 0, stream>>>(caWk, caWv, fW1, fW2, wkvT, w1T, w2T);
  k_gemm_mem<<<dim3(256, 4), 256, 0, stream>>>(encb, wpeT, wpeb, img, memb);

  // ---- phase 0: text block
  k_linear256<<<32, 256, 0, stream>>>(txtf, tpW, tpb, txt, BB * NTXT, 0);
  XPA a0 = {tWk, tbk, tK, tWv, tbv, tV, nullptr, nullptr, nullptr};
  k_xproj<<<dim3(32, 2), 256, 0, stream>>>(txt, a0);
  k_init_x<<<MM, 256, 0, stream>>>(qe, ptok, x);
  XPA a1 = {tWq, tbq, tA, nullptr, nullptr, nullptr, nullptr, nullptr, nullptr};
  k_xproj<<<dim3(101, 1), 256, 0, stream>>>(x, a1);
  k_attn_small<<<64, 128, 0, stream>>>(tA, tK, tV, tB, NTXT);
  k_o_ln<0, 0><<<101, 256, 0, stream>>>(tB, tWo, tbo, x, tlng, tlnb, x, nullptr,
                                        nullptr, nullptr, nullptr, nullptr, nullptr, nullptr);

  for (int i = 0; i < NLAY; ++i) {
    size_t wo = (size_t)i * DD * DD;
    int iD = i * DD;
    // self-attention
    XPA as = {saWq + wo, sabq + iD, tA, saWk + wo, sabk + iD, tB, saWv + wo, sabv + iD, tC};
    k_xproj<<<dim3(101, 3), 256, 0, stream>>>(x, as);
    k_attn_small<<<64, 128, 0, stream>>>(tA, tB, tC, tD, TT);
    // o-proj + LN1 + ca-q-proj + posq
    k_o_ln<1, 0><<<101, 256, 0, stream>>>(tD, saWo + wo, sabo + iD, x, ln1g + iD,
                                          ln1b + iD, x, nullptr, caWq + wo, cabq + iD,
                                          tA, posW + (size_t)i * DD * 3, posb + i * 3, posq);
    // cross-attention
    k_gemm_kv<<<dim3(256, 8), 256, 0, stream>>>(memb, wkvT + wo, wkvT + (size_t)(6 + i) * DD * DD,
                                                cabk + iD, cabv + iD, Kb, Vt);
    k_cross_mfma<<<dim3(64, KC), 256, 0, stream>>>(tA, Kb, Vt, posq, pm4, beta + i * NH, pacc, pl);
    k_cross_merge<<<dim3(64, 13), 256, 0, stream>>>(pacc, pl, tB);
    // ca-o-proj + LN2 + bf16 copy for FFN
    k_o_ln<0, 1><<<101, 256, 0, stream>>>(tB, caWo + wo, cabo + iD, x, ln2g + iD,
                                          ln2b + iD, x, xb, nullptr, nullptr, nullptr,
                                          nullptr, nullptr, nullptr);
    // FFN
    k_ffn1<<<dim3(7, 32), 256, 0, stream>>>(xb, w1T + (size_t)i * DD * FFD, fb1 + i * FFD, hb);
    k_ffn2sk<<<dim3(7, 4, 8), 256, 0, stream>>>(hb, w2T + (size_t)i * DD * FFD, fp2);
    k_red_ln3<<<MM, 256, 0, stream>>>(fp2, fb2 + iD, x, ln3g + iD, ln3b + iD, x);
  }

  // ---- epilogue
  k_fin<<<MM, 256, 0, stream>>>(x, fing, finb, (float*)d_out, pres);
  k_linear256<<<1, 256, 0, stream>>>(pres, pW1, pb1, ph1, BB, 1);
  k_linear256<<<1, 256, 0, stream>>>(ph1, pW2, pb2, ph2, BB, 1);
  k_logit<<<1, 256, 0, stream>>>(ph2, pW3, pb3, (float*)d_out + (size_t)BB * NQRY * DD);
}

// Round 4
// 898.359 us; speedup vs baseline: 13.9701x; 1.4507x over previous
//
#include <hip/hip_runtime.h>
#include <math.h>

#define DD 256
#define NH 8
#define HDIM 32
#define NLAY 6
#define NQRY 100
#define TT 101
#define BB 8
#define NN 4096
#define NTXT 32
#define FFD 2048
#define MM (BB*TT)      // 808
#define MMP 896         // 7*128 padded rows
#define BNN (BB*NN)     // 32768
#define KC 8
#define KPC (NN/KC)     // 512
#define D2 (DD*DD)

typedef __bf16 bf16x8 __attribute__((ext_vector_type(8)));
typedef float f32x4v __attribute__((ext_vector_type(4)));
typedef unsigned int u32x4 __attribute__((ext_vector_type(4)));
typedef unsigned int u32x2 __attribute__((ext_vector_type(2)));

__device__ __forceinline__ ushort f2b(float f) {
  unsigned u = __builtin_bit_cast(unsigned, f);
  u += 0x7FFF + ((u >> 16) & 1);
  return (ushort)(u >> 16);
}
__device__ __forceinline__ unsigned pk2(float lo, float hi) {
  return (unsigned)f2b(lo) | ((unsigned)f2b(hi) << 16);
}
__device__ __forceinline__ f32x4v mfma16(bf16x8 a, bf16x8 b, f32x4v c) {
  return __builtin_amdgcn_mfma_f32_16x16x32_bf16(a, b, c, 0, 0, 0);
}

// ---------------- shared MFMA GEMM core: 128x64 tile, BK=64, swizzled LDS ----------------
__device__ __forceinline__ void gemm_core(const ushort* __restrict__ A, size_t lda,
                                          const ushort* __restrict__ Bt, size_t ldb,
                                          int m0, int n0, int kBeg, int kEnd,
                                          char* AsB, char* BsB, int t,
                                          f32x4v acc[2][4]) {
  int w = t >> 6, l = t & 63, lq = l & 15, lg = l >> 4;
  int acol = (t & 7) * 8;
  for (int k0 = kBeg; k0 < kEnd; k0 += 64) {
    __syncthreads();
#pragma unroll
    for (int p = 0; p < 4; ++p) {
      int row = (t >> 3) + p * 32;
      u32x4 v = *(const u32x4*)(A + (size_t)(m0 + row) * lda + k0 + acol);
      *(u32x4*)(AsB + row * 128 + ((acol * 2) ^ ((row & 7) << 4))) = v;
    }
#pragma unroll
    for (int p = 0; p < 2; ++p) {
      int row = (t >> 3) + p * 32;
      u32x4 v = *(const u32x4*)(Bt + (size_t)(n0 + row) * ldb + k0 + acol);
      *(u32x4*)(BsB + row * 128 + ((acol * 2) ^ ((row & 7) << 4))) = v;
    }
    __syncthreads();
#pragma unroll
    for (int ks = 0; ks < 2; ++ks) {
      bf16x8 af[2], bfr[4];
#pragma unroll
      for (int mt = 0; mt < 2; ++mt) {
        int row = w * 32 + mt * 16 + lq;
        int kb = ks * 64 + lg * 16;
        af[mt] = __builtin_bit_cast(
            bf16x8, *(const u32x4*)(AsB + row * 128 + (kb ^ ((row & 7) << 4))));
      }
#pragma unroll
      for (int nt = 0; nt < 4; ++nt) {
        int row = nt * 16 + lq;
        int kb = ks * 64 + lg * 16;
        bfr[nt] = __builtin_bit_cast(
            bf16x8, *(const u32x4*)(BsB + row * 128 + (kb ^ ((row & 7) << 4))));
      }
#pragma unroll
      for (int mt = 0; mt < 2; ++mt)
#pragma unroll
        for (int nt = 0; nt < 4; ++nt) acc[mt][nt] = mfma16(af[mt], bfr[nt], acc[mt][nt]);
    }
  }
}

// ---------------------------------------------------------------- enc bf16 [BNN][64]
__global__ __launch_bounds__(256) void k_enc(const float* __restrict__ pm,
                                             ushort* __restrict__ encb) {
  int t = threadIdx.x;
  int row = blockIdx.x * 32 + (t >> 3);
  int kb = (t & 7) * 8;
  ushort o[8];
#pragma unroll
  for (int u = 0; u < 8; ++u) {
    int k = kb + u;
    float val = 0.f;
    if (k < 60) {
      int c = k / 20, jj = k % 20;
      float f = (float)(1 << (jj % 10));
      float a = pm[(size_t)row * 3 + c] * f;
      val = (jj < 10) ? sinf(a) : cosf(a);
    }
    o[u] = f2b(val);
  }
  *(u32x4*)(encb + (size_t)row * 64 + kb) = *(const u32x4*)o;
}

// -------------------------------------------------- wpeT bf16 [256][64] (pad K 60->64)
__global__ __launch_bounds__(256) void k_wpet(const float* __restrict__ wpeW,
                                              ushort* __restrict__ wpeT) {
  int n = blockIdx.x * 16 + (threadIdx.x >> 4);
  int k = (threadIdx.x & 15) * 4;
  ushort o[4];
#pragma unroll
  for (int u = 0; u < 4; ++u) {
    int kk = k + u;
    o[u] = (kk < 60) ? f2b(wpeW[(size_t)kk * DD + n]) : (ushort)0;
  }
  *(u32x2*)(wpeT + (size_t)n * 64 + k) = *(const u32x2*)o;
}

// -------------------------- memb = bf16(enc@wpeW + wpeb + img) via MFMA, grid (256,4)
__global__ __launch_bounds__(256) void k_gemm_mem(const ushort* __restrict__ encb,
                                                  const ushort* __restrict__ wpeT,
                                                  const float* __restrict__ wpeb,
                                                  const float* __restrict__ img,
                                                  ushort* __restrict__ memb) {
  __shared__ __align__(16) char AsB[16384];
  __shared__ __align__(16) char BsB[8192];
  int m0 = blockIdx.x * 128, n0 = blockIdx.y * 64;
  f32x4v acc[2][4] = {};
  gemm_core(encb, 64, wpeT, 64, m0, n0, 0, 64, AsB, BsB, threadIdx.x, acc);
  int t = threadIdx.x, w = t >> 6, l = t & 63, lq = l & 15, lg = l >> 4;
#pragma unroll
  for (int nt = 0; nt < 4; ++nt) {
    int n = n0 + nt * 16 + lq;
    float bv = wpeb[n];
#pragma unroll
    for (int mt = 0; mt < 2; ++mt) {
      int rowg = m0 + w * 32 + mt * 16 + lg * 4;
      f32x4v a = acc[mt][nt];
#pragma unroll
      for (int r = 0; r < 4; ++r)
        memb[(size_t)(rowg + r) * DD + n] = f2b(a[r] + bv + img[(size_t)(rowg + r) * DD + n]);
    }
  }
}

// ------------------------------- ALL weight transposes f32->bf16^T in ONE dispatch
struct T2BArgs {
  const float* fam[8];     // saWq,saWk,saWv,saWo,caWq,caWk,caWv,caWo (6 each)
  const float* single[5];  // tpW,tWq,tWk,tWv,tWo
  const float* fW1; const float* fW2;
  ushort* wT; ushort* w1T; ushort* w2T;
};
__global__ __launch_bounds__(256) void k_t2b_all(T2BArgs a) {
  __shared__ ushort T[64][72];
  int id = blockIdx.x;
  const float* src; ushort* dst; int K, N, k0, n0;
  if (id < 768) {
    int fam = id / 96, rem = id % 96, mi = rem >> 4, ti = rem & 15;
    src = a.fam[fam] + (size_t)mi * D2;
    dst = a.wT + (size_t)(fam * 6 + mi) * D2;
    K = DD; N = DD; k0 = (ti >> 2) * 64; n0 = (ti & 3) * 64;
  } else if (id < 848) {
    int j = (id - 768) >> 4, ti = (id - 768) & 15;
    src = a.single[j];
    dst = a.wT + (size_t)(48 + j) * D2;
    K = DD; N = DD; k0 = (ti >> 2) * 64; n0 = (ti & 3) * 64;
  } else if (id < 1616) {
    int t2 = id - 848, mi = t2 >> 7, ti = t2 & 127;
    src = a.fW1 + (size_t)mi * DD * FFD;
    dst = a.w1T + (size_t)mi * DD * FFD;
    K = DD; N = FFD; k0 = (ti >> 5) * 64; n0 = (ti & 31) * 64;
  } else {
    int t2 = id - 1616, mi = t2 >> 7, ti = t2 & 127;
    src = a.fW2 + (size_t)mi * DD * FFD;
    dst = a.w2T + (size_t)mi * DD * FFD;
    K = FFD; N = DD; k0 = (ti >> 2) * 64; n0 = (ti & 3) * 64;
  }
  int t = threadIdx.x;
  int kk = t >> 4, nn4 = (t & 15) * 4;
#pragma unroll
  for (int p = 0; p < 4; ++p) {
    int krow = kk + p * 16;
    float4 v = *(const float4*)(src + (size_t)(k0 + krow) * N + n0 + nn4);
    T[nn4 + 0][krow] = f2b(v.x);
    T[nn4 + 1][krow] = f2b(v.y);
    T[nn4 + 2][krow] = f2b(v.z);
    T[nn4 + 3][krow] = f2b(v.w);
  }
  __syncthreads();
  int nn = t >> 3, kk8 = (t & 7) * 8;
#pragma unroll
  for (int p = 0; p < 2; ++p) {
    int nrow = nn + p * 32;
    u32x4 v = *(const u32x4*)(&T[nrow][kk8]);
    *(u32x4*)(dst + (size_t)(n0 + nrow) * K + k0 + kk8) = v;
  }
}

// ------------------------------------------------------------ pm4 = (x, y, z, |p|^2)
__global__ __launch_bounds__(256) void k_pm4(const float* __restrict__ pm,
                                             float4* __restrict__ pm4) {
  int i = blockIdx.x * 256 + threadIdx.x;
  float x = pm[(size_t)i * 3 + 0];
  float y = pm[(size_t)i * 3 + 1];
  float z = pm[(size_t)i * 3 + 2];
  float4 v;
  v.x = x; v.y = y; v.z = z; v.w = x * x + y * y + z * z;
  pm4[i] = v;
}

// ------------------------------------------------------------ flat f32 -> bf16
__global__ __launch_bounds__(256) void k_f2b(const float* __restrict__ in,
                                             ushort* __restrict__ out, int n) {
  int i = (blockIdx.x * 256 + threadIdx.x) * 4;
  if (i + 3 < n) {
    float4 v = *(const float4*)(in + i);
    out[i + 0] = f2b(v.x);
    out[i + 1] = f2b(v.y);
    out[i + 2] = f2b(v.z);
    out[i + 3] = f2b(v.w);
  }
}

// --------------------- generic MFMA GEMM (K=256): OM 0=f32, 1=bf16, 2=bf16+relu
template <int OM>
__global__ __launch_bounds__(256) void k_gemm_gen(const ushort* __restrict__ A,
                                                  const ushort* __restrict__ Bt,
                                                  const float* __restrict__ bias,
                                                  void* __restrict__ C, int Nc) {
  __shared__ __align__(16) char AsB[16384];
  __shared__ __align__(16) char BsB[8192];
  int m0 = blockIdx.x * 128, n0 = blockIdx.y * 64;
  f32x4v acc[2][4] = {};
  gemm_core(A, 256, Bt, 256, m0, n0, 0, 256, AsB, BsB, threadIdx.x, acc);
  int t = threadIdx.x, w = t >> 6, l = t & 63, lq = l & 15, lg = l >> 4;
#pragma unroll
  for (int nt = 0; nt < 4; ++nt) {
    int n = n0 + nt * 16 + lq;
    float bv = bias[n];
#pragma unroll
    for (int mt = 0; mt < 2; ++mt) {
      int rowg = m0 + w * 32 + mt * 16 + lg * 4;
      f32x4v a = acc[mt][nt];
      a[0] += bv; a[1] += bv; a[2] += bv; a[3] += bv;
      if (OM == 2) {
        a[0] = fmaxf(a[0], 0.f); a[1] = fmaxf(a[1], 0.f);
        a[2] = fmaxf(a[2], 0.f); a[3] = fmaxf(a[3], 0.f);
      }
      if (OM == 0) {
        float* Cf = (float*)C;
#pragma unroll
        for (int r = 0; r < 4; ++r) Cf[(size_t)(rowg + r) * Nc + n] = a[r];
      } else {
        ushort* Cb = (ushort*)C;
#pragma unroll
        for (int r = 0; r < 4; ++r) Cb[(size_t)(rowg + r) * Nc + n] = f2b(a[r]);
      }
    }
  }
}

// --------------------- QKV projection in one dispatch: grid (7, 12), f32 outs
__global__ __launch_bounds__(256) void k_gemm_qkv(
    const ushort* __restrict__ A, const ushort* __restrict__ Bq,
    const ushort* __restrict__ Bk, const ushort* __restrict__ Bv,
    const float* __restrict__ bq, const float* __restrict__ bk,
    const float* __restrict__ bv, float* __restrict__ Oq,
    float* __restrict__ Ok, float* __restrict__ Ov) {
  __shared__ __align__(16) char AsB[16384];
  __shared__ __align__(16) char BsB[8192];
  int sel = blockIdx.y >> 2;
  int n0 = (blockIdx.y & 3) * 64;
  int m0 = blockIdx.x * 128;
  const ushort* Bt = sel == 0 ? Bq : (sel == 1 ? Bk : Bv);
  const float* bias = sel == 0 ? bq : (sel == 1 ? bk : bv);
  float* O = sel == 0 ? Oq : (sel == 1 ? Ok : Ov);
  f32x4v acc[2][4] = {};
  gemm_core(A, 256, Bt, 256, m0, n0, 0, 256, AsB, BsB, threadIdx.x, acc);
  int t = threadIdx.x, w = t >> 6, l = t & 63, lq = l & 15, lg = l >> 4;
#pragma unroll
  for (int nt = 0; nt < 4; ++nt) {
    int n = n0 + nt * 16 + lq;
    float bvv = bias[n];
#pragma unroll
    for (int mt = 0; mt < 2; ++mt) {
      int rowg = m0 + w * 32 + mt * 16 + lg * 4;
      f32x4v a = acc[mt][nt];
#pragma unroll
      for (int r = 0; r < 4; ++r) O[(size_t)(rowg + r) * DD + n] = a[r] + bvv;
    }
  }
}

// ------- o-proj + residual + LN fused: 64x256 tile (full row), grid 14; opt. posq
template <int QPROJ>
__global__ __launch_bounds__(256) void k_gemm_o_ln(
    const ushort* __restrict__ A, const ushort* __restrict__ WoT,
    const float* __restrict__ bo, const float* __restrict__ xres,
    const float* __restrict__ g, const float* __restrict__ be,
    float* __restrict__ xout, ushort* __restrict__ xbout,
    const float* __restrict__ Wp, const float* __restrict__ bp,
    float* __restrict__ pqout) {
  __shared__ __align__(16) char AsB[8192];    // 64 rows x 128B
  __shared__ __align__(16) char BsB[32768];   // 256 rows x 128B
  int m0 = blockIdx.x * 64;
  int t = threadIdx.x, w = t >> 6, l = t & 63, lq = l & 15, lg = l >> 4;
  int acol = (t & 7) * 8;
  f32x4v acc[16] = {};
  for (int k0 = 0; k0 < 256; k0 += 64) {
    __syncthreads();
#pragma unroll
    for (int p = 0; p < 2; ++p) {
      int row = (t >> 3) + p * 32;
      u32x4 v = *(const u32x4*)(A + (size_t)(m0 + row) * 256 + k0 + acol);
      *(u32x4*)(AsB + row * 128 + ((acol * 2) ^ ((row & 7) << 4))) = v;
    }
#pragma unroll
    for (int p = 0; p < 8; ++p) {
      int row = (t >> 3) + p * 32;
      u32x4 v = *(const u32x4*)(WoT + (size_t)row * 256 + k0 + acol);
      *(u32x4*)(BsB + row * 128 + ((acol * 2) ^ ((row & 7) << 4))) = v;
    }
    __syncthreads();
#pragma unroll
    for (int ks = 0; ks < 2; ++ks) {
      int kb = ks * 64 + lg * 16;
      int arow = w * 16 + lq;
      bf16x8 af = __builtin_bit_cast(
          bf16x8, *(const u32x4*)(AsB + arow * 128 + (kb ^ ((arow & 7) << 4))));
#pragma unroll
      for (int nt = 0; nt < 16; ++nt) {
        int brow = nt * 16 + lq;
        bf16x8 bf = __builtin_bit_cast(
            bf16x8, *(const u32x4*)(BsB + brow * 128 + (kb ^ ((brow & 7) << 4))));
        acc[nt] = mfma16(af, bf, acc[nt]);
      }
    }
  }
  int rowb = m0 + w * 16 + lg * 4;
  float s[4] = {}, s2[4] = {};
#pragma unroll
  for (int nt = 0; nt < 16; ++nt) {
    int col = nt * 16 + lq;
    float bv = bo[col];
    f32x4v a = acc[nt];
#pragma unroll
    for (int r = 0; r < 4; ++r) {
      a[r] += bv + xres[(size_t)(rowb + r) * DD + col];
      s[r] += a[r];
      s2[r] += a[r] * a[r];
    }
    acc[nt] = a;
  }
#pragma unroll
  for (int r = 0; r < 4; ++r) {
#pragma unroll
    for (int o = 1; o < 16; o <<= 1) {
      s[r] += __shfl_xor(s[r], o, 64);
      s2[r] += __shfl_xor(s2[r], o, 64);
    }
  }
  float mu[4], inv[4];
#pragma unroll
  for (int r = 0; r < 4; ++r) {
    mu[r] = s[r] * (1.f / DD);
    float var = s2[r] * (1.f / DD) - mu[r] * mu[r];
    inv[r] = rsqrtf(var + 1e-5f);
  }
  float pp0[4] = {}, pp1[4] = {}, pp2[4] = {};
#pragma unroll
  for (int nt = 0; nt < 16; ++nt) {
    int col = nt * 16 + lq;
    float gd = g[col], bd = be[col];
    float w0 = 0.f, w1 = 0.f, w2 = 0.f;
    if (QPROJ) { w0 = Wp[col * 3]; w1 = Wp[col * 3 + 1]; w2 = Wp[col * 3 + 2]; }
#pragma unroll
    for (int r = 0; r < 4; ++r) {
      float ln = (acc[nt][r] - mu[r]) * inv[r] * gd + bd;
      xout[(size_t)(rowb + r) * DD + col] = ln;
      xbout[(size_t)(rowb + r) * DD + col] = f2b(ln);
      if (QPROJ) { pp0[r] += ln * w0; pp1[r] += ln * w1; pp2[r] += ln * w2; }
    }
  }
  if (QPROJ) {
#pragma unroll
    for (int r = 0; r < 4; ++r) {
#pragma unroll
      for (int o = 1; o < 16; o <<= 1) {
        pp0[r] += __shfl_xor(pp0[r], o, 64);
        pp1[r] += __shfl_xor(pp1[r], o, 64);
        pp2[r] += __shfl_xor(pp2[r], o, 64);
      }
      if (lq == 0) {
        pqout[(size_t)(rowb + r) * 3 + 0] = pp0[r] + bp[0];
        pqout[(size_t)(rowb + r) * 3 + 1] = pp1[r] + bp[1];
        pqout[(size_t)(rowb + r) * 3 + 2] = pp2[r] + bp[2];
      }
    }
  }
}

// -------------------------------------------- x init (f32 + bf16 mirror)
__global__ __launch_bounds__(256) void k_init_x(const float* __restrict__ qe,
                                                const float* __restrict__ pt,
                                                float* __restrict__ x,
                                                ushort* __restrict__ xb) {
  int r = blockIdx.x, d = threadIdx.x;
  int t = r % TT;
  float v = (t < NQRY) ? qe[t * DD + d] : pt[d];
  x[(size_t)r * DD + d] = v;
  xb[(size_t)r * DD + d] = f2b(v);
}

// ------------------------- small attention, f32 in, bf16 out, fixed-base softmax
__global__ __launch_bounds__(128) void k_attn_small(const float* __restrict__ q,
                                                    const float* __restrict__ k,
                                                    const float* __restrict__ v,
                                                    ushort* __restrict__ out,
                                                    int NK) {
  int bh = blockIdx.x;
  int b = bh >> 3, h = bh & 7;
  __shared__ float Ks[TT][HDIM];
  __shared__ float Vs[TT][HDIM];
  for (int i = threadIdx.x; i < NK * HDIM; i += 128) {
    int n = i >> 5, j = i & 31;
    Ks[n][j] = k[(size_t)(b * NK + n) * DD + h * HDIM + j];
    Vs[n][j] = v[(size_t)(b * NK + n) * DD + h * HDIM + j];
  }
  __syncthreads();
  int t = threadIdx.x;
  if (t >= TT) return;
  float qv[HDIM];
  const float* qp = q + (size_t)(b * TT + t) * DD + h * HDIM;
#pragma unroll
  for (int j = 0; j < HDIM; ++j) qv[j] = qp[j];
  const float sc = 0.17677669529663687f * 1.4426950408889634f;
  float l = 0.f, acc[HDIM] = {};
  for (int n = 0; n < NK; ++n) {
    float s = 0.f;
#pragma unroll
    for (int j = 0; j < HDIM; ++j) s += qv[j] * Ks[n][j];
    float p = exp2f(s * sc);
    l += p;
#pragma unroll
    for (int j = 0; j < HDIM; ++j) acc[j] += p * Vs[n][j];
  }
  float inv = 1.f / l;
  ushort* op = out + (size_t)(b * TT + t) * DD + h * HDIM;
#pragma unroll
  for (int j = 0; j < HDIM; ++j) op[j] = f2b(acc[j] * inv);
}

// ------------- fused K+V projection of memb: 128x128 tile, grid (256, 4)
__global__ __launch_bounds__(256) void k_gemm_kv(const ushort* __restrict__ A,
                                                 const ushort* __restrict__ Btk,
                                                 const ushort* __restrict__ Btv,
                                                 const float* __restrict__ bk,
                                                 const float* __restrict__ bv,
                                                 ushort* __restrict__ Kb,
                                                 ushort* __restrict__ Vt) {
  __shared__ __align__(16) char AsB[16384];
  __shared__ __align__(16) char BsB[16384];
  int isV = blockIdx.y >= 2;
  int n0 = (blockIdx.y & 1) * 128;
  int m0 = blockIdx.x * 128;
  const ushort* Bt = isV ? Btv : Btk;
  int t = threadIdx.x, w = t >> 6, l = t & 63, lq = l & 15, lg = l >> 4;
  int acol = (t & 7) * 8;
  f32x4v acc[2][8] = {};
  for (int k0 = 0; k0 < 256; k0 += 64) {
    __syncthreads();
#pragma unroll
    for (int p = 0; p < 4; ++p) {
      int row = (t >> 3) + p * 32;
      u32x4 va = *(const u32x4*)(A + (size_t)(m0 + row) * 256 + k0 + acol);
      *(u32x4*)(AsB + row * 128 + ((acol * 2) ^ ((row & 7) << 4))) = va;
      u32x4 vb = *(const u32x4*)(Bt + (size_t)(n0 + row) * 256 + k0 + acol);
      *(u32x4*)(BsB + row * 128 + ((acol * 2) ^ ((row & 7) << 4))) = vb;
    }
    __syncthreads();
#pragma unroll
    for (int ks = 0; ks < 2; ++ks) {
      int kb = ks * 64 + lg * 16;
      bf16x8 af[2], bfr[8];
#pragma unroll
      for (int mt = 0; mt < 2; ++mt) {
        int row = w * 32 + mt * 16 + lq;
        af[mt] = __builtin_bit_cast(
            bf16x8, *(const u32x4*)(AsB + row * 128 + (kb ^ ((row & 7) << 4))));
      }
#pragma unroll
      for (int nt = 0; nt < 8; ++nt) {
        int row = nt * 16 + lq;
        bfr[nt] = __builtin_bit_cast(
            bf16x8, *(const u32x4*)(BsB + row * 128 + (kb ^ ((row & 7) << 4))));
      }
#pragma unroll
      for (int mt = 0; mt < 2; ++mt)
#pragma unroll
        for (int nt = 0; nt < 8; ++nt) acc[mt][nt] = mfma16(af[mt], bfr[nt], acc[mt][nt]);
    }
  }
  const float* bias = isV ? bv : bk;
#pragma unroll
  for (int nt = 0; nt < 8; ++nt) {
    int n = n0 + nt * 16 + lq;
    float bvv = bias[n];
#pragma unroll
    for (int mt = 0; mt < 2; ++mt) {
      int rowg = m0 + w * 32 + mt * 16 + lg * 4;
      f32x4v a = acc[mt][nt];
      a[0] += bvv; a[1] += bvv; a[2] += bvv; a[3] += bvv;
      if (!isV) {
#pragma unroll
        for (int r = 0; r < 4; ++r) Kb[(size_t)(rowg + r) * DD + n] = f2b(a[r]);
      } else {
        int b = rowg >> 12, key = rowg & 4095;
        int h = n >> 5, dd = n & 31;
        u32x2 pv;
        pv[0] = pk2(a[0], a[1]);
        pv[1] = pk2(a[2], a[3]);
        *(u32x2*)(Vt + ((size_t)((b * 8 + h) * 32 + dd) * 4096 + key)) = pv;
      }
    }
  }
}

// ----------------------- FFN2 split-K: partials P[z][row][col], grid (7, 4, 8)
__global__ __launch_bounds__(256) void k_ffn2sk(const ushort* __restrict__ A,
                                                const ushort* __restrict__ Bt,
                                                float* __restrict__ P) {
  __shared__ __align__(16) char AsB[16384];
  __shared__ __align__(16) char BsB[8192];
  int m0 = blockIdx.x * 128, n0 = blockIdx.y * 64, z = blockIdx.z;
  f32x4v acc[2][4] = {};
  gemm_core(A, FFD, Bt, FFD, m0, n0, z * 256, z * 256 + 256, AsB, BsB, threadIdx.x, acc);
  int t = threadIdx.x, w = t >> 6, l = t & 63, lq = l & 15, lg = l >> 4;
#pragma unroll
  for (int nt = 0; nt < 4; ++nt) {
    int n = n0 + nt * 16 + lq;
#pragma unroll
    for (int mt = 0; mt < 2; ++mt) {
      int rowg = m0 + w * 32 + mt * 16 + lg * 4;
      f32x4v a = acc[mt][nt];
#pragma unroll
      for (int r = 0; r < 4; ++r)
        P[((size_t)z * MMP + rowg + r) * DD + n] = a[r];
    }
  }
}

// -------------------- FFN2 reduce + bias + residual + LN3 -> x, xb
__global__ __launch_bounds__(256) void k_red_ln3(const float* __restrict__ P,
                                                 const float* __restrict__ bias,
                                                 const float* __restrict__ xres,
                                                 const float* __restrict__ g,
                                                 const float* __restrict__ be,
                                                 float* __restrict__ xout,
                                                 ushort* __restrict__ xbout) {
  int row = blockIdx.x, d = threadIdx.x;
  float a = xres[(size_t)row * DD + d] + bias[d];
#pragma unroll
  for (int z = 0; z < 8; ++z) a += P[((size_t)z * MMP + row) * DD + d];
  float s = a, s2 = a * a;
#pragma unroll
  for (int o = 1; o < 64; o <<= 1) {
    s += __shfl_xor(s, o, 64);
    s2 += __shfl_xor(s2, o, 64);
  }
  __shared__ float ws[4], ws2[4];
  int wid = d >> 6;
  if ((d & 63) == 0) { ws[wid] = s; ws2[wid] = s2; }
  __syncthreads();
  s = ws[0] + ws[1] + ws[2] + ws[3];
  s2 = ws2[0] + ws2[1] + ws2[2] + ws2[3];
  float m = s * (1.f / DD);
  float var = s2 * (1.f / DD) - m * m;
  float inv = rsqrtf(var + 1e-5f);
  float r_ = (a - m) * inv * g[d] + be[d];
  xout[(size_t)row * DD + d] = r_;
  xbout[(size_t)row * DD + d] = f2b(r_);
}

// ------------------- MFMA flash cross-attention with distance bias (verified R2/R3)
__global__ __launch_bounds__(256) void k_cross_mfma(
    const float* __restrict__ Q, const ushort* __restrict__ Kb,
    const ushort* __restrict__ Vt, const float* __restrict__ posq,
    const float4* __restrict__ pm4, const float* __restrict__ betaL,
    float* __restrict__ pacc, float* __restrict__ pl) {
  int bh = blockIdx.x, kc = blockIdx.y;
  int b = bh >> 3, h = bh & 7;
  int t = threadIdx.x, w = t >> 6, l = t & 63, lq = l & 15, lg = l >> 4;
  const float L2E = 1.4426950408889634f;
  const float c1 = 0.17677669529663687f * L2E;
  float spb = log1pf(expf(betaL[h]));
  float cb = spb * L2E;

  __shared__ float4 pm4s[KPC];
  __shared__ ushort Plds[4][2][16][40];

  int kbase = b * NN + kc * KPC;
  for (int i = t; i < KPC; i += 256) pm4s[i] = pm4[kbase + i];
  __syncthreads();

  const f32x4v Z = {0.f, 0.f, 0.f, 0.f};
  bf16x8 qfb[2];
  float a0[2], px[2], py[2], pz[2];
  f32x4v oacc[2][2] = {};
  float lsum[2] = {0.f, 0.f};

#pragma unroll
  for (int qi = 0; qi < 2; ++qi) {
    int qt = w * 2 + qi;
    int qidx = qt * 16 + lq;
    int qc = qidx < TT ? qidx : TT - 1;
    size_t xr = (size_t)(b * TT + qc);
    const float* qp = Q + xr * 256 + h * 32 + lg * 8;
    float4 q0 = *(const float4*)qp;
    float4 q1 = *(const float4*)(qp + 4);
    u32x4 qv;
    qv[0] = pk2(q0.x * c1, q0.y * c1);
    qv[1] = pk2(q0.z * c1, q0.w * c1);
    qv[2] = pk2(q1.x * c1, q1.y * c1);
    qv[3] = pk2(q1.z * c1, q1.w * c1);
    qfb[qi] = __builtin_bit_cast(bf16x8, qv);
    float qx = posq[xr * 3 + 0], qy = posq[xr * 3 + 1], qz = posq[xr * 3 + 2];
    a0[qi] = -cb * (qx * qx + qy * qy + qz * qz);
    px[qi] = 2.f * cb * qx;
    py[qi] = 2.f * cb * qy;
    pz[qi] = 2.f * cb * qz;
  }

  for (int kk = 0; kk < KPC; kk += 32) {
    bf16x8 kf[2], vf[2];
#pragma unroll
    for (int t2 = 0; t2 < 2; ++t2)
      kf[t2] = __builtin_bit_cast(
          bf16x8, *(const u32x4*)(Kb + (size_t)(kbase + kk + t2 * 16 + lq) * 256 +
                                  h * 32 + lg * 8));
#pragma unroll
    for (int dt = 0; dt < 2; ++dt)
      vf[dt] = __builtin_bit_cast(
          bf16x8, *(const u32x4*)(Vt + (size_t)(bh * 32 + dt * 16 + lq) * 4096 +
                                  kc * KPC + kk + lg * 8));
    float bx[2][4], by[2][4], bz[2][4], b0[2][4];
#pragma unroll
    for (int t2 = 0; t2 < 2; ++t2)
#pragma unroll
      for (int r = 0; r < 4; ++r) {
        float4 pv = pm4s[kk + t2 * 16 + lg * 4 + r];
        bx[t2][r] = pv.x; by[t2][r] = pv.y; bz[t2][r] = pv.z;
        b0[t2][r] = cb * pv.w;
      }
#pragma unroll
    for (int qi = 0; qi < 2; ++qi) {
      f32x4v s0 = mfma16(kf[0], qfb[qi], Z);
      f32x4v s1 = mfma16(kf[1], qfb[qi], Z);
      float p[2][4];
#pragma unroll
      for (int t2 = 0; t2 < 2; ++t2) {
#pragma unroll
        for (int r = 0; r < 4; ++r) {
          float sv = (t2 == 0) ? s0[r] : s1[r];
          float bias = fmaf(px[qi], bx[t2][r],
                       fmaf(py[qi], by[t2][r],
                       fmaf(pz[qi], bz[t2][r], a0[qi] - b0[t2][r])));
          p[t2][r] = exp2f(sv + bias);
        }
        lsum[qi] += (p[t2][0] + p[t2][1]) + (p[t2][2] + p[t2][3]);
      }
      u32x2 w0, w1;
      w0[0] = pk2(p[0][0], p[0][1]);
      w0[1] = pk2(p[0][2], p[0][3]);
      w1[0] = pk2(p[1][0], p[1][1]);
      w1[1] = pk2(p[1][2], p[1][3]);
      *(u32x2*)(&Plds[w][qi][lq][lg * 4]) = w0;
      *(u32x2*)(&Plds[w][qi][lq][16 + lg * 4]) = w1;
      bf16x8 pf = __builtin_bit_cast(bf16x8, *(const u32x4*)(&Plds[w][qi][lq][lg * 8]));
      oacc[qi][0] = mfma16(vf[0], pf, oacc[qi][0]);
      oacc[qi][1] = mfma16(vf[1], pf, oacc[qi][1]);
    }
  }

#pragma unroll
  for (int qi = 0; qi < 2; ++qi) {
    float lv = lsum[qi];
    lv += __shfl_xor(lv, 16, 64);
    lv += __shfl_xor(lv, 32, 64);
    int qt = w * 2 + qi;
    int qidx = qt * 16 + lq;
    if (qidx < TT) {
      size_t o = ((size_t)(kc * 64 + bh) * TT + qidx) * 32;
#pragma unroll
      for (int dt = 0; dt < 2; ++dt) {
        f32x4v a = oacc[qi][dt];
        float4 st;
        st.x = a[0]; st.y = a[1]; st.z = a[2]; st.w = a[3];
        *(float4*)(pacc + o + dt * 16 + lg * 4) = st;
      }
      if (lg == 0) pl[(size_t)(kc * 64 + bh) * TT + qidx] = lv;
    }
  }
}

// -------------------------- merge key-chunk partials -> bf16 attn out
__global__ __launch_bounds__(256) void k_cross_merge(const float* __restrict__ pacc,
                                                     const float* __restrict__ pl,
                                                     ushort* __restrict__ out) {
  int bh = blockIdx.x;
  int b = bh >> 3, h = bh & 7;
  int q8 = blockIdx.y * 8 + (threadIdx.x >> 5);
  int j = threadIdx.x & 31;
  if (q8 >= TT) return;
  float sa = 0.f, sl = 0.f;
  for (int kc = 0; kc < KC; ++kc) {
    sa += pacc[(((size_t)kc * 64 + bh) * TT + q8) * HDIM + j];
    sl += pl[((size_t)kc * 64 + bh) * TT + q8];
  }
  out[((size_t)(b * TT + q8)) * DD + h * HDIM + j] = f2b(sa / sl);
}

// ------------------------ final LN + scatter to hs / pres
__global__ __launch_bounds__(256) void k_fin(const float* __restrict__ x,
                                             const float* __restrict__ g,
                                             const float* __restrict__ be,
                                             float* __restrict__ hs,
                                             float* __restrict__ pres) {
  int row = blockIdx.x, d = threadIdx.x;
  int b = row / TT, tq = row % TT;
  float v = x[(size_t)row * DD + d];
  float s = v, s2 = v * v;
#pragma unroll
  for (int o = 1; o < 64; o <<= 1) {
    s += __shfl_xor(s, o, 64);
    s2 += __shfl_xor(s2, o, 64);
  }
  __shared__ float ws[4], ws2[4];
  int wid = d >> 6;
  if ((d & 63) == 0) { ws[wid] = s; ws2[wid] = s2; }
  __syncthreads();
  s = ws[0] + ws[1] + ws[2] + ws[3];
  s2 = ws2[0] + ws2[1] + ws2[2] + ws2[3];
  float m = s * (1.f / DD);
  float var = s2 * (1.f / DD) - m * m;
  float inv = rsqrtf(var + 1e-5f);
  float r = (v - m) * inv * g[d] + be[d];
  if (tq < NQRY) hs[((size_t)(b * NQRY + tq)) * DD + d] = r;
  else pres[(size_t)b * DD + d] = r;
}

// ------------------------------------------------- presence MLP helpers (tiny, f32)
__global__ __launch_bounds__(256) void k_linear256(const float* __restrict__ x,
                                                   const float* __restrict__ W,
                                                   const float* __restrict__ b,
                                                   float* __restrict__ y,
                                                   int Mr, int relu) {
  int r0 = blockIdx.x * 8;
  int d = threadIdx.x;
  __shared__ float xs[8][DD];
  for (int i = threadIdx.x; i < 8 * DD; i += 256) {
    int r = i >> 8, k = i & 255;
    xs[r][k] = (r0 + r < Mr) ? x[(size_t)(r0 + r) * DD + k] : 0.f;
  }
  __syncthreads();
  float acc[8] = {};
  for (int k = 0; k < DD; ++k) {
    float w = W[k * DD + d];
#pragma unroll
    for (int r = 0; r < 8; ++r) acc[r] += xs[r][k] * w;
  }
  float bb = b[d];
#pragma unroll
  for (int r = 0; r < 8; ++r) {
    if (r0 + r < Mr) {
      float v = acc[r] + bb;
      if (relu) v = fmaxf(v, 0.f);
      y[(size_t)(r0 + r) * DD + d] = v;
    }
  }
}

__global__ __launch_bounds__(256) void k_logit(const float* __restrict__ h2,
                                               const float* __restrict__ W3,
                                               const float* __restrict__ b3,
                                               float* __restrict__ out) {
  int r = threadIdx.x >> 5, lane = threadIdx.x & 31;
  float s = 0.f;
  for (int k = lane; k < DD; k += 32) s += h2[r * DD + k] * W3[k];
#pragma unroll
  for (int o = 16; o; o >>= 1) s += __shfl_xor(s, o, 32);
  if (lane == 0) out[r] = s + b3[0];
}

// =======================================================================================
extern "C" void kernel_launch(void* const* d_in, const int* in_sizes, int n_in,
                              void* d_out, int out_size, void* d_ws, size_t ws_size,
                              hipStream_t stream) {
  (void)in_sizes; (void)n_in; (void)out_size; (void)ws_size;
  auto F = [&](int i) { return (const float*)d_in[i]; };
  const float* img   = F(0);
  const float* txtf  = F(1);
  const float* pm    = F(2);
  const float* qe    = F(3);
  const float* ptok  = F(4);
  const float* tpW   = F(5);
  const float* tpb   = F(6);
  const float* tWq   = F(7);  const float* tbq = F(8);
  const float* tWk   = F(9);  const float* tbk = F(10);
  const float* tWv   = F(11); const float* tbv = F(12);
  const float* tWo   = F(13); const float* tbo = F(14);
  const float* tlng  = F(15); const float* tlnb = F(16);
  const float* wpeW  = F(17); const float* wpeb = F(18);
  const float* saWq  = F(19); const float* sabq = F(20);
  const float* saWk  = F(21); const float* sabk = F(22);
  const float* saWv  = F(23); const float* sabv = F(24);
  const float* saWo  = F(25); const float* sabo = F(26);
  const float* caWq  = F(27); const float* cabq = F(28);
  const float* caWk  = F(29); const float* cabk = F(30);
  const float* caWv  = F(31); const float* cabv = F(32);
  const float* caWo  = F(33); const float* cabo = F(34);
  const float* fW1   = F(35); const float* fb1 = F(36);
  const float* fW2   = F(37); const float* fb2 = F(38);
  const float* ln1g  = F(39); const float* ln1b = F(40);
  const float* ln2g  = F(41); const float* ln2b = F(42);
  const float* ln3g  = F(43); const float* ln3b = F(44);
  const float* posW  = F(45); const float* posb = F(46);
  const float* beta  = F(47);
  const float* fing  = F(48); const float* finb = F(49);
  const float* pW1   = F(50); const float* pb1 = F(51);
  const float* pW2   = F(52); const float* pb2 = F(53);
  const float* pW3   = F(54); const float* pb3 = F(55);

  char* wp = (char*)d_ws;
  auto alloc = [&](size_t bytes) {
    char* p = wp;
    wp += (bytes + 255) & ~(size_t)255;
    return (void*)p;
  };
  ushort* encb = (ushort*)alloc((size_t)BNN * 64 * 2);
  ushort* wpeT = (ushort*)alloc((size_t)DD * 64 * 2);
  ushort* memb = (ushort*)alloc((size_t)BNN * DD * 2);
  ushort* Kb   = (ushort*)alloc((size_t)BNN * DD * 2);
  ushort* Vt   = (ushort*)alloc((size_t)64 * 32 * 4096 * 2);
  ushort* wT   = (ushort*)alloc((size_t)53 * D2 * 2);
  ushort* w1T  = (ushort*)alloc((size_t)6 * FFD * DD * 2);
  ushort* w2T  = (ushort*)alloc((size_t)6 * DD * FFD * 2);
  ushort* xb   = (ushort*)alloc((size_t)MMP * DD * 2);
  ushort* hb   = (ushort*)alloc((size_t)MMP * FFD * 2);
  ushort* tDb  = (ushort*)alloc((size_t)MMP * DD * 2);
  ushort* txtb = (ushort*)alloc((size_t)BB * NTXT * DD * 2);
  ushort* txtb2= (ushort*)alloc((size_t)BB * NTXT * DD * 2);
  float* fp2  = (float*)alloc((size_t)8 * MMP * DD * 4);
  float* x    = (float*)alloc((size_t)MMP * DD * 4);
  float* tA   = (float*)alloc((size_t)MMP * DD * 4);
  float* tB   = (float*)alloc((size_t)MMP * DD * 4);
  float* tC   = (float*)alloc((size_t)MMP * DD * 4);
  float* tK   = (float*)alloc((size_t)BB * NTXT * DD * 4);
  float* tV   = (float*)alloc((size_t)BB * NTXT * DD * 4);
  float* pacc = (float*)alloc((size_t)KC * 64 * TT * HDIM * 4);
  float* pl   = (float*)alloc((size_t)KC * 64 * TT * 4);
  float* posq = (float*)alloc((size_t)4096 * 4);
  float4* pm4 = (float4*)alloc((size_t)BNN * 16);
  float* pres = (float*)alloc((size_t)BB * DD * 4);
  float* ph1  = (float*)alloc((size_t)BB * DD * 4);
  float* ph2  = (float*)alloc((size_t)BB * DD * 4);

  // ---- prologue
  k_enc<<<BNN / 32, 256, 0, stream>>>(pm, encb);
  k_wpet<<<16, 256, 0, stream>>>(wpeW, wpeT);
  k_pm4<<<BNN / 256, 256, 0, stream>>>(pm, pm4);
  T2BArgs ta;
  ta.fam[0] = saWq; ta.fam[1] = saWk; ta.fam[2] = saWv; ta.fam[3] = saWo;
  ta.fam[4] = caWq; ta.fam[5] = caWk; ta.fam[6] = caWv; ta.fam[7] = caWo;
  ta.single[0] = tpW; ta.single[1] = tWq; ta.single[2] = tWk;
  ta.single[3] = tWv; ta.single[4] = tWo;
  ta.fW1 = fW1; ta.fW2 = fW2; ta.wT = wT; ta.w1T = w1T; ta.w2T = w2T;
  k_t2b_all<<<2384, 256, 0, stream>>>(ta);
  k_gemm_mem<<<dim3(256, 4), 256, 0, stream>>>(encb, wpeT, wpeb, img, memb);

  // ---- phase 0: text block
  k_f2b<<<(BB * NTXT * DD) / 1024, 256, 0, stream>>>(txtf, txtb, BB * NTXT * DD);
  k_gemm_gen<1><<<dim3(2, 4), 256, 0, stream>>>(txtb, wT + (size_t)48 * D2, tpb, txtb2, DD);
  k_gemm_gen<0><<<dim3(2, 4), 256, 0, stream>>>(txtb2, wT + (size_t)50 * D2, tbk, tK, DD);
  k_gemm_gen<0><<<dim3(2, 4), 256, 0, stream>>>(txtb2, wT + (size_t)51 * D2, tbv, tV, DD);
  k_init_x<<<MM, 256, 0, stream>>>(qe, ptok, x, xb);
  k_gemm_gen<0><<<dim3(7, 4), 256, 0, stream>>>(xb, wT + (size_t)49 * D2, tbq, tA, DD);
  k_attn_small<<<64, 128, 0, stream>>>(tA, tK, tV, tDb, NTXT);
  k_gemm_o_ln<0><<<14, 256, 0, stream>>>(tDb, wT + (size_t)52 * D2, tbo, x, tlng, tlnb,
                                         x, xb, nullptr, nullptr, nullptr);

  for (int i = 0; i < NLAY; ++i) {
    int iD = i * DD;
    // self-attention
    k_gemm_qkv<<<dim3(7, 12), 256, 0, stream>>>(
        xb, wT + (size_t)(0 + i) * D2, wT + (size_t)(6 + i) * D2, wT + (size_t)(12 + i) * D2,
        sabq + iD, sabk + iD, sabv + iD, tA, tB, tC);
    k_attn_small<<<64, 128, 0, stream>>>(tA, tB, tC, tDb, TT);
    k_gemm_o_ln<1><<<14, 256, 0, stream>>>(tDb, wT + (size_t)(18 + i) * D2, sabo + iD,
                                           x, ln1g + iD, ln1b + iD, x, xb,
                                           posW + (size_t)i * DD * 3, posb + i * 3, posq);
    // cross-attention
    k_gemm_gen<0><<<dim3(7, 4), 256, 0, stream>>>(xb, wT + (size_t)(24 + i) * D2,
                                                  cabq + iD, tA, DD);
    k_gemm_kv<<<dim3(256, 4), 256, 0, stream>>>(memb, wT + (size_t)(30 + i) * D2,
                                                wT + (size_t)(36 + i) * D2,
                                                cabk + iD, cabv + iD, Kb, Vt);
    k_cross_mfma<<<dim3(64, KC), 256, 0, stream>>>(tA, Kb, Vt, posq, pm4,
                                                   beta + i * NH, pacc, pl);
    k_cross_merge<<<dim3(64, 13), 256, 0, stream>>>(pacc, pl, tDb);
    k_gemm_o_ln<0><<<14, 256, 0, stream>>>(tDb, wT + (size_t)(42 + i) * D2, cabo + iD,
                                           x, ln2g + iD, ln2b + iD, x, xb,
                                           nullptr, nullptr, nullptr);
    // FFN
    k_gemm_gen<2><<<dim3(7, 32), 256, 0, stream>>>(xb, w1T + (size_t)i * DD * FFD,
                                                   fb1 + i * FFD, hb, FFD);
    k_ffn2sk<<<dim3(7, 4, 8), 256, 0, stream>>>(hb, w2T + (size_t)i * DD * FFD, fp2);
    k_red_ln3<<<MM, 256, 0, stream>>>(fp2, fb2 + iD, x, ln3g + iD, ln3b + iD, x, xb);
  }

  // ---- epilogue
  k_fin<<<MM, 256, 0, stream>>>(x, fing, finb, (float*)d_out, pres);
  k_linear256<<<1, 256, 0, stream>>>(pres, pW1, pb1, ph1, BB, 1);
  k_linear256<<<1, 256, 0, stream>>>(ph1, pW2, pb2, ph2, BB, 1);
  k_logit<<<1, 256, 0, stream>>>(ph2, pW3, pb3, (float*)d_out + (size_t)BB * NQRY * DD);
}